// Round 1
// baseline (217.632 us; speedup 1.0000x reference)
//
#include <hip/hip_runtime.h>
#include <hip/hip_bf16.h>
#include <stdint.h>

#define B_SZ 16384
#define D_SZ 512
#define N_SZ 1024

using bf16x8 = __attribute__((ext_vector_type(8))) short;
using f32x4  = __attribute__((ext_vector_type(4))) float;

__device__ __forceinline__ unsigned short f2bf(float f) {
    unsigned u = __builtin_bit_cast(unsigned, f);
    unsigned r = (u + 0x7FFFu + ((u >> 16) & 1u)) >> 16;
    return (unsigned short)r;
}
__device__ __forceinline__ float bf2f(unsigned short h) {
    return __builtin_bit_cast(float, (unsigned)h << 16);
}

// ---- prep: W -> bf16 hi/lo, transposed copies, row norms ----
__global__ __launch_bounds__(256) void prep_w(
    const float* __restrict__ W, unsigned short* __restrict__ wh,
    unsigned short* __restrict__ wl, unsigned short* __restrict__ wth,
    unsigned short* __restrict__ wtl) {
    int idx = blockIdx.x * 256 + threadIdx.x;  // < N_SZ*D_SZ = 524288
    float f = W[idx];
    unsigned short h = f2bf(f);
    unsigned short l = f2bf(f - bf2f(h));
    wh[idx] = h; wl[idx] = l;
    int n = idx >> 9, d = idx & 511;
    wth[d * N_SZ + n] = h;
    wtl[d * N_SZ + n] = l;
}

__global__ __launch_bounds__(64) void prep_ww(const float* __restrict__ W,
                                              float* __restrict__ ww) {
    int n = blockIdx.x, lane = threadIdx.x;
    float s = 0.f;
    for (int i = 0; i < 8; ++i) {
        float f = W[n * D_SZ + i * 64 + lane];
        s += f * f;
    }
    for (int off = 32; off; off >>= 1) s += __shfl_xor(s, off);
    if (lane == 0) ww[n] = s;
}

// ---- GEMM1: L[b,n] = 4*(x_b . w_n) - 2*||w_n||^2  (logits, xx-term dropped) ----
__global__ __launch_bounds__(256, 2) void gemm1(
    const float* __restrict__ X, const unsigned short* __restrict__ wh,
    const unsigned short* __restrict__ wl, const float* __restrict__ ww,
    float* __restrict__ L) {
    __shared__ short Ah[128][40], Al[128][40], Bh[128][40], Bl[128][40];
    const int tid = threadIdx.x;
    const int wid = tid >> 6, lane = tid & 63;
    const int bn0 = blockIdx.x * 128;  // n
    const int bm0 = blockIdx.y * 128;  // b
    const int m0 = (wid >> 1) * 64, n0 = (wid & 1) * 64;
    const int rA = lane & 15, krun = (lane >> 4) * 8;

    f32x4 acc[4][4];
    for (int mi = 0; mi < 4; ++mi)
        for (int ni = 0; ni < 4; ++ni) acc[mi][ni] = (f32x4){0.f, 0.f, 0.f, 0.f};

    for (int kt = 0; kt < 16; ++kt) {
        const int gk = kt * 32;
        // stage X (f32 -> bf16 hi/lo)
        {
            const int r0 = tid >> 3, kc = (tid & 7) * 4;
            for (int i = 0; i < 4; ++i) {
                int row = r0 + 32 * i;
                const float4 v = *reinterpret_cast<const float4*>(
                    &X[(size_t)(bm0 + row) * D_SZ + gk + kc]);
                unsigned short h0 = f2bf(v.x), h1 = f2bf(v.y), h2 = f2bf(v.z), h3 = f2bf(v.w);
                short4 hs = make_short4((short)h0, (short)h1, (short)h2, (short)h3);
                short4 ls = make_short4((short)f2bf(v.x - bf2f(h0)), (short)f2bf(v.y - bf2f(h1)),
                                        (short)f2bf(v.z - bf2f(h2)), (short)f2bf(v.w - bf2f(h3)));
                *reinterpret_cast<short4*>(&Ah[row][kc]) = hs;
                *reinterpret_cast<short4*>(&Al[row][kc]) = ls;
            }
        }
        // stage W hi/lo (already bf16)
        {
            const int seg = (tid & 3) * 8;
            for (int i = 0; i < 2; ++i) {
                int row = (tid >> 2) + 64 * i;
                const int4 vh = *reinterpret_cast<const int4*>(
                    &wh[(size_t)(bn0 + row) * D_SZ + gk + seg]);
                *reinterpret_cast<int4*>(&Bh[row][seg]) = vh;
                const int4 vl = *reinterpret_cast<const int4*>(
                    &wl[(size_t)(bn0 + row) * D_SZ + gk + seg]);
                *reinterpret_cast<int4*>(&Bl[row][seg]) = vl;
            }
        }
        __syncthreads();
        bf16x8 afh[4], afl[4], bfh[4], bfl[4];
        for (int mi = 0; mi < 4; ++mi) {
            afh[mi] = *reinterpret_cast<const bf16x8*>(&Ah[m0 + mi * 16 + rA][krun]);
            afl[mi] = *reinterpret_cast<const bf16x8*>(&Al[m0 + mi * 16 + rA][krun]);
        }
        for (int ni = 0; ni < 4; ++ni) {
            bfh[ni] = *reinterpret_cast<const bf16x8*>(&Bh[n0 + ni * 16 + rA][krun]);
            bfl[ni] = *reinterpret_cast<const bf16x8*>(&Bl[n0 + ni * 16 + rA][krun]);
        }
        for (int mi = 0; mi < 4; ++mi)
            for (int ni = 0; ni < 4; ++ni) {
                acc[mi][ni] = __builtin_amdgcn_mfma_f32_16x16x32_bf16(afh[mi], bfh[ni], acc[mi][ni], 0, 0, 0);
                acc[mi][ni] = __builtin_amdgcn_mfma_f32_16x16x32_bf16(afh[mi], bfl[ni], acc[mi][ni], 0, 0, 0);
                acc[mi][ni] = __builtin_amdgcn_mfma_f32_16x16x32_bf16(afl[mi], bfh[ni], acc[mi][ni], 0, 0, 0);
            }
        __syncthreads();
    }
    for (int mi = 0; mi < 4; ++mi)
        for (int ni = 0; ni < 4; ++ni) {
            int nn = bn0 + n0 + ni * 16 + (lane & 15);
            float wwn = ww[nn];
            int bb = bm0 + m0 + mi * 16 + (lane >> 4) * 4;
            f32x4 a = acc[mi][ni];
            for (int r = 0; r < 4; ++r)
                L[(size_t)(bb + r) * N_SZ + nn] = 4.f * a[r] - 2.f * wwn;
        }
}

// ---- per-row softmax (row-axis and col-axis), renorm, pack a -> bf16 hi/lo (in place) ----
__global__ __launch_bounds__(256) void softsm(float* __restrict__ L) {
    __shared__ float S[32][33];
    __shared__ float cmax[32], csum[32], rmax[32], rsum[32];
    __shared__ float Tp[4];
    const int t = threadIdx.x;
    const size_t base = (size_t)blockIdx.x * N_SZ;
    const float4 v = *reinterpret_cast<const float4*>(&L[base + (size_t)t * 4]);
    const int i = t >> 3, j0 = (t & 7) * 4;
    S[i][j0] = v.x; S[i][j0 + 1] = v.y; S[i][j0 + 2] = v.z; S[i][j0 + 3] = v.w;
    __syncthreads();
    if (t < 32) {  // column j = t: reduce over i (grid axis 0)
        float m = -1e30f;
        for (int ii = 0; ii < 32; ++ii) m = fmaxf(m, S[ii][t]);
        float s = 0.f;
        for (int ii = 0; ii < 32; ++ii) s += expf(S[ii][t] - m);
        cmax[t] = m; csum[t] = s;
    } else if (t < 64) {  // row i = t-32: reduce over j (grid axis 1)
        int ii = t - 32;
        float m = -1e30f;
        for (int jj = 0; jj < 32; ++jj) m = fmaxf(m, S[ii][jj]);
        float s = 0.f;
        for (int jj = 0; jj < 32; ++jj) s += expf(S[ii][jj] - m);
        rmax[ii] = m; rsum[ii] = s;
    }
    __syncthreads();
    float tv[4], part = 0.f;
    for (int c = 0; c < 4; ++c) {
        int j = j0 + c;
        float l = S[i][j];
        float tt = expf(l - cmax[j]) * expf(l - rmax[i]) / (csum[j] * rsum[i]);
        tv[c] = tt;
        part += tt;
    }
    for (int off = 32; off; off >>= 1) part += __shfl_xor(part, off);
    if ((t & 63) == 0) Tp[t >> 6] = part;
    __syncthreads();
    const float T = Tp[0] + Tp[1] + Tp[2] + Tp[3];
    const float inv = 1.f / (T + 1e-8f);
    unsigned pk[4];
    for (int c = 0; c < 4; ++c) {
        float a = tv[c] * inv;
        unsigned short h = f2bf(a);
        unsigned short l2 = f2bf(a - bf2f(h));
        pk[c] = (unsigned)h | ((unsigned)l2 << 16);
    }
    uint4 o = make_uint4(pk[0], pk[1], pk[2], pk[3]);
    *reinterpret_cast<uint4*>(reinterpret_cast<unsigned*>(L) + base + (size_t)t * 4) = o;
}

// ---- GEMM2: Y[b,d] = sum_n a[b,n] * W[n,d]  (a packed hi/lo bf16, W^T bf16 hi/lo) ----
__global__ __launch_bounds__(256, 2) void gemm2(
    const unsigned* __restrict__ Ap, const unsigned short* __restrict__ wth,
    const unsigned short* __restrict__ wtl, float* __restrict__ Y) {
    __shared__ short Ah[128][40], Al[128][40], Bh[128][40], Bl[128][40];
    const int tid = threadIdx.x;
    const int wid = tid >> 6, lane = tid & 63;
    const int bn0 = blockIdx.x * 128;  // d
    const int bm0 = blockIdx.y * 128;  // b
    const int m0 = (wid >> 1) * 64, n0 = (wid & 1) * 64;
    const int rA = lane & 15, krun = (lane >> 4) * 8;

    f32x4 acc[4][4];
    for (int mi = 0; mi < 4; ++mi)
        for (int ni = 0; ni < 4; ++ni) acc[mi][ni] = (f32x4){0.f, 0.f, 0.f, 0.f};

    for (int kt = 0; kt < 32; ++kt) {
        const int gk = kt * 32;  // n offset
        // stage A (packed u32 -> hi/lo bf16)
        {
            const int r0 = tid >> 3, g4 = (tid & 7) * 4;
            for (int i = 0; i < 4; ++i) {
                int row = r0 + 32 * i;
                const uint4 v = *reinterpret_cast<const uint4*>(
                    &Ap[(size_t)(bm0 + row) * N_SZ + gk + g4]);
                short4 hs = make_short4((short)(v.x & 0xffffu), (short)(v.y & 0xffffu),
                                        (short)(v.z & 0xffffu), (short)(v.w & 0xffffu));
                short4 ls = make_short4((short)(v.x >> 16), (short)(v.y >> 16),
                                        (short)(v.z >> 16), (short)(v.w >> 16));
                *reinterpret_cast<short4*>(&Ah[row][g4]) = hs;
                *reinterpret_cast<short4*>(&Al[row][g4]) = ls;
            }
        }
        // stage B = W^T
        {
            const int seg = (tid & 3) * 8;
            for (int i = 0; i < 2; ++i) {
                int row = (tid >> 2) + 64 * i;
                const int4 vh = *reinterpret_cast<const int4*>(
                    &wth[(size_t)(bn0 + row) * N_SZ + gk + seg]);
                *reinterpret_cast<int4*>(&Bh[row][seg]) = vh;
                const int4 vl = *reinterpret_cast<const int4*>(
                    &wtl[(size_t)(bn0 + row) * N_SZ + gk + seg]);
                *reinterpret_cast<int4*>(&Bl[row][seg]) = vl;
            }
        }
        __syncthreads();
        bf16x8 afh[4], afl[4], bfh[4], bfl[4];
        for (int mi = 0; mi < 4; ++mi) {
            afh[mi] = *reinterpret_cast<const bf16x8*>(&Ah[m0 + mi * 16 + rA][krun]);
            afl[mi] = *reinterpret_cast<const bf16x8*>(&Al[m0 + mi * 16 + rA][krun]);
        }
        for (int ni = 0; ni < 4; ++ni) {
            bfh[ni] = *reinterpret_cast<const bf16x8*>(&Bh[n0 + ni * 16 + rA][krun]);
            bfl[ni] = *reinterpret_cast<const bf16x8*>(&Bl[n0 + ni * 16 + rA][krun]);
        }
        for (int mi = 0; mi < 4; ++mi)
            for (int ni = 0; ni < 4; ++ni) {
                acc[mi][ni] = __builtin_amdgcn_mfma_f32_16x16x32_bf16(afh[mi], bfh[ni], acc[mi][ni], 0, 0, 0);
                acc[mi][ni] = __builtin_amdgcn_mfma_f32_16x16x32_bf16(afl[mi], bfh[ni], acc[mi][ni], 0, 0, 0);
                acc[mi][ni] = __builtin_amdgcn_mfma_f32_16x16x32_bf16(afh[mi], bfl[ni], acc[mi][ni], 0, 0, 0);
            }
        __syncthreads();
    }
    for (int mi = 0; mi < 4; ++mi)
        for (int ni = 0; ni < 4; ++ni) {
            int dd = bn0 + n0 + ni * 16 + (lane & 15);
            int bb = bm0 + m0 + mi * 16 + (lane >> 4) * 4;
            f32x4 a = acc[mi][ni];
            for (int r = 0; r < 4; ++r)
                Y[(size_t)(bb + r) * D_SZ + dd] = a[r];
        }
}

extern "C" void kernel_launch(void* const* d_in, const int* in_sizes, int n_in,
                              void* d_out, int out_size, void* d_ws, size_t ws_size,
                              hipStream_t stream) {
    (void)in_sizes; (void)n_in; (void)out_size; (void)ws_size;
    const float* X = (const float*)d_in[0];
    const float* W = (const float*)d_in[1];
    float* Y = (float*)d_out;
    char* ws = (char*)d_ws;

    float* L = (float*)ws;                                        // 64 MB: logits, then packed a
    unsigned short* wh  = (unsigned short*)(ws + (size_t)64 * 1024 * 1024);
    unsigned short* wl  = wh + (size_t)N_SZ * D_SZ;
    unsigned short* wth = wl + (size_t)N_SZ * D_SZ;
    unsigned short* wtl = wth + (size_t)N_SZ * D_SZ;
    float* ww = (float*)(wtl + (size_t)N_SZ * D_SZ);

    prep_w<<<(N_SZ * D_SZ) / 256, 256, 0, stream>>>(W, wh, wl, wth, wtl);
    prep_ww<<<N_SZ, 64, 0, stream>>>(W, ww);
    gemm1<<<dim3(N_SZ / 128, B_SZ / 128), 256, 0, stream>>>(X, wh, wl, ww, L);
    softsm<<<B_SZ, 256, 0, stream>>>(L);
    gemm2<<<dim3(D_SZ / 128, B_SZ / 128), 256, 0, stream>>>((const unsigned*)L, wth, wtl, Y);
}

// Round 2
// 156.990 us; speedup vs baseline: 1.3863x; 1.3863x over previous
//
#include <hip/hip_runtime.h>
#include <hip/hip_bf16.h>
#include <stdint.h>

#define B_SZ 16384
#define D_SZ 512
#define N_SZ 1024

using f16x8 = __attribute__((ext_vector_type(8))) _Float16;
using f16x4 = __attribute__((ext_vector_type(4))) _Float16;
using f32x4 = __attribute__((ext_vector_type(4))) float;

typedef unsigned int u32_as1 __attribute__((address_space(1)));
typedef unsigned int u32_as3 __attribute__((address_space(3)));

__device__ __forceinline__ void gload16(const void* g, void* lds_base) {
    __builtin_amdgcn_global_load_lds((const u32_as1*)g, (u32_as3*)lds_base, 16, 0, 0);
}

// ---- prep: W -> fp16 plane, fp16 transposed plane, row norms ----
__global__ __launch_bounds__(256) void prep_w(
    const float* __restrict__ W, _Float16* __restrict__ wh,
    _Float16* __restrict__ wt, float* __restrict__ ww) {
    const int n = blockIdx.x;   // 0..1023
    const int t = threadIdx.x;  // 0..255, 2 elements each
    __shared__ float part[4];
    const float2 v = *reinterpret_cast<const float2*>(&W[(size_t)n * D_SZ + t * 2]);
    _Float16 h0 = (_Float16)v.x, h1 = (_Float16)v.y;
    wh[(size_t)n * D_SZ + t * 2] = h0;
    wh[(size_t)n * D_SZ + t * 2 + 1] = h1;
    wt[(size_t)(t * 2) * N_SZ + n] = h0;
    wt[(size_t)(t * 2 + 1) * N_SZ + n] = h1;
    float s = v.x * v.x + v.y * v.y;
    for (int o = 32; o; o >>= 1) s += __shfl_xor(s, o);
    if ((t & 63) == 0) part[t >> 6] = s;
    __syncthreads();
    if (t == 0) ww[n] = part[0] + part[1] + part[2] + part[3];
}

// ---- GEMM1: L[b,n] = 4*(x_b . w_n) - 2*||w_n||^2 ----
// 128x128 tile, BK=32, 4 waves. A (X) reg-staged f32->fp16 with XOR-swizzled
// ds_write; B (wh fp16) via global_load_lds with XOR'd per-lane source addr.
__global__ __launch_bounds__(256, 3) void gemm1(
    const float* __restrict__ X, const _Float16* __restrict__ wh,
    const float* __restrict__ ww, float* __restrict__ L) {
    __shared__ _Float16 As[128 * 32];
    __shared__ _Float16 Bs[128 * 32];
    const int tid = threadIdx.x;
    const int wid = tid >> 6, lane = tid & 63;
    const int bn0 = blockIdx.x * 128;
    const int bm0 = blockIdx.y * 128;
    const int m0 = (wid >> 1) * 64, n0 = (wid & 1) * 64;
    const int rA = lane & 15;
    const int cbr = (lane >> 4) * 16;            // fragment read byte-col
    const int rswz = ((rA >> 1) & 3) << 4;       // read swizzle (row-dependent bits only from rA)

    // A staging: thread t stages row ar, 16 elements starting at ac
    const int ar = tid >> 1;
    const int ac = (tid & 1) * 16;
    const size_t xoff = (size_t)(bm0 + ar) * D_SZ + ac;
    const int aswz = ((ar >> 1) & 3) << 4;
    char* const As_b = (char*)As;
    char* const Bs_b = (char*)Bs;
    char* const aw0 = As_b + ar * 64 + ((ac * 2) ^ aswz);
    char* const aw1 = As_b + ar * 64 + ((ac * 2 + 16) ^ aswz);

    // B staging (per-wave gload): two segments per wave
    const int br0 = (wid * 2) * 16 + (lane >> 2);
    const int br1 = (wid * 2 + 1) * 16 + (lane >> 2);
    const int sg0 = ((lane & 3) ^ ((br0 >> 1) & 3)) * 8;
    const int sg1 = ((lane & 3) ^ ((br1 >> 1) & 3)) * 8;

    f32x4 acc[4][4];
    for (int mi = 0; mi < 4; ++mi)
        for (int ni = 0; ni < 4; ++ni) acc[mi][ni] = (f32x4){0.f, 0.f, 0.f, 0.f};

    for (int kt = 0; kt < 16; ++kt) {
        const int gk = kt * 32;
        // B: async global->LDS
        gload16(&wh[(size_t)(bn0 + br0) * D_SZ + gk + sg0], Bs_b + (wid * 2) * 1024);
        gload16(&wh[(size_t)(bn0 + br1) * D_SZ + gk + sg1], Bs_b + (wid * 2 + 1) * 1024);
        // A: f32 -> fp16, swizzled ds_write
        const float4 x0 = *reinterpret_cast<const float4*>(&X[xoff + gk]);
        const float4 x1 = *reinterpret_cast<const float4*>(&X[xoff + gk + 4]);
        const float4 x2 = *reinterpret_cast<const float4*>(&X[xoff + gk + 8]);
        const float4 x3 = *reinterpret_cast<const float4*>(&X[xoff + gk + 12]);
        f16x8 h0 = {(_Float16)x0.x, (_Float16)x0.y, (_Float16)x0.z, (_Float16)x0.w,
                    (_Float16)x1.x, (_Float16)x1.y, (_Float16)x1.z, (_Float16)x1.w};
        f16x8 h1 = {(_Float16)x2.x, (_Float16)x2.y, (_Float16)x2.z, (_Float16)x2.w,
                    (_Float16)x3.x, (_Float16)x3.y, (_Float16)x3.z, (_Float16)x3.w};
        *reinterpret_cast<f16x8*>(aw0) = h0;
        *reinterpret_cast<f16x8*>(aw1) = h1;
        __syncthreads();
        f16x8 af[4], bf[4];
        for (int mi = 0; mi < 4; ++mi)
            af[mi] = *reinterpret_cast<const f16x8*>(As_b + (m0 + mi * 16 + rA) * 64 + (cbr ^ rswz));
        for (int ni = 0; ni < 4; ++ni)
            bf[ni] = *reinterpret_cast<const f16x8*>(Bs_b + (n0 + ni * 16 + rA) * 64 + (cbr ^ rswz));
        for (int mi = 0; mi < 4; ++mi)
            for (int ni = 0; ni < 4; ++ni)
                acc[mi][ni] = __builtin_amdgcn_mfma_f32_16x16x32_f16(af[mi], bf[ni], acc[mi][ni], 0, 0, 0);
        __syncthreads();
    }
    for (int mi = 0; mi < 4; ++mi)
        for (int ni = 0; ni < 4; ++ni) {
            const int nn = bn0 + n0 + ni * 16 + rA;
            const float wwn = ww[nn];
            const int bb = bm0 + m0 + mi * 16 + (lane >> 4) * 4;
            const f32x4 a = acc[mi][ni];
            for (int r = 0; r < 4; ++r)
                L[(size_t)(bb + r) * N_SZ + nn] = 4.f * a[r] - 2.f * wwn;
        }
}

// ---- softmax over both grid axes, renorm, write a as fp16 in-place ----
// Block p handles L rows 2p, 2p+1; writes 4KB of fp16 a into the SECOND half
// of its own 8KB pair-region (race-free; all reads happen before writes).
// a16 row b lives at byte offset 8192*(b>>1) + 4096 + (b&1)*2048.
__global__ __launch_bounds__(512) void softsm(float* __restrict__ L) {
    __shared__ float S[2][32][33];
    __shared__ float cmax[2][32], csum[2][32], rmax[2][32], rsum[2][32];
    __shared__ float Tp[2][4];
    const int h = threadIdx.x >> 8;
    const int t = threadIdx.x & 255;
    const size_t row = (size_t)blockIdx.x * 2 + h;
    const float4 v = *reinterpret_cast<const float4*>(&L[row * N_SZ + (size_t)t * 4]);
    const int i = t >> 3, j0 = (t & 7) * 4;
    S[h][i][j0] = v.x; S[h][i][j0 + 1] = v.y; S[h][i][j0 + 2] = v.z; S[h][i][j0 + 3] = v.w;
    __syncthreads();
    if (t < 32) {  // column t: reduce over grid axis 0
        float m = -1e30f;
        for (int ii = 0; ii < 32; ++ii) m = fmaxf(m, S[h][ii][t]);
        float s = 0.f;
        for (int ii = 0; ii < 32; ++ii) s += expf(S[h][ii][t] - m);
        cmax[h][t] = m; csum[h][t] = s;
    } else if (t < 64) {  // row t-32: reduce over grid axis 1
        const int ii = t - 32;
        float m = -1e30f;
        for (int jj = 0; jj < 32; ++jj) m = fmaxf(m, S[h][ii][jj]);
        float s = 0.f;
        for (int jj = 0; jj < 32; ++jj) s += expf(S[h][ii][jj] - m);
        rmax[h][ii] = m; rsum[h][ii] = s;
    }
    __syncthreads();
    float tv[4], part = 0.f;
    const float cm0 = cmax[h][j0], cm1 = cmax[h][j0 + 1], cm2 = cmax[h][j0 + 2], cm3 = cmax[h][j0 + 3];
    const float rm = rmax[h][i], rs = rsum[h][i];
    tv[0] = expf(2.f * S[h][i][j0] - cm0 - rm) / (csum[h][j0] * rs);
    tv[1] = expf(2.f * S[h][i][j0 + 1] - cm1 - rm) / (csum[h][j0 + 1] * rs);
    tv[2] = expf(2.f * S[h][i][j0 + 2] - cm2 - rm) / (csum[h][j0 + 2] * rs);
    tv[3] = expf(2.f * S[h][i][j0 + 3] - cm3 - rm) / (csum[h][j0 + 3] * rs);
    part = tv[0] + tv[1] + tv[2] + tv[3];
    for (int o = 32; o; o >>= 1) part += __shfl_xor(part, o);
    if ((t & 63) == 0) Tp[h][t >> 6] = part;
    __syncthreads();
    const float T = Tp[h][0] + Tp[h][1] + Tp[h][2] + Tp[h][3];
    const float inv = 1.f / (T + 1e-8f);
    f16x4 o = {(_Float16)(tv[0] * inv), (_Float16)(tv[1] * inv),
               (_Float16)(tv[2] * inv), (_Float16)(tv[3] * inv)};
    char* out = (char*)L + (size_t)blockIdx.x * 8192 + 4096 + (size_t)h * 2048 + (size_t)(i * 32 + j0) * 2;
    *reinterpret_cast<f16x4*>(out) = o;
}

// ---- GEMM2: Y[b,d] = sum_n a[b,n] * W[n,d]; both operands via gload_lds ----
__global__ __launch_bounds__(256, 3) void gemm2(
    const char* __restrict__ aBytes, const _Float16* __restrict__ wt,
    float* __restrict__ Y) {
    __shared__ _Float16 As[128 * 32];
    __shared__ _Float16 Bs[128 * 32];
    const int tid = threadIdx.x;
    const int wid = tid >> 6, lane = tid & 63;
    const int bn0 = blockIdx.x * 128;  // d
    const int bm0 = blockIdx.y * 128;  // b
    const int m0 = (wid >> 1) * 64, n0 = (wid & 1) * 64;
    const int rA = lane & 15;
    const int cbr = (lane >> 4) * 16;
    const int rswz = ((rA >> 1) & 3) << 4;

    const int br0 = (wid * 2) * 16 + (lane >> 2);
    const int br1 = (wid * 2 + 1) * 16 + (lane >> 2);
    const int sg0 = ((lane & 3) ^ ((br0 >> 1) & 3)) * 8;
    const int sg1 = ((lane & 3) ^ ((br1 >> 1) & 3)) * 8;
    char* const As_b = (char*)As;
    char* const Bs_b = (char*)Bs;
    // a16 strided row bases
    const int ab0 = bm0 + br0, ab1 = bm0 + br1;
    const size_t abase0 = (size_t)(ab0 >> 1) * 8192 + 4096 + (size_t)(ab0 & 1) * 2048;
    const size_t abase1 = (size_t)(ab1 >> 1) * 8192 + 4096 + (size_t)(ab1 & 1) * 2048;

    f32x4 acc[4][4];
    for (int mi = 0; mi < 4; ++mi)
        for (int ni = 0; ni < 4; ++ni) acc[mi][ni] = (f32x4){0.f, 0.f, 0.f, 0.f};

    for (int kt = 0; kt < 32; ++kt) {
        const int gk = kt * 32;
        gload16(aBytes + abase0 + (size_t)(gk + sg0) * 2, As_b + (wid * 2) * 1024);
        gload16(aBytes + abase1 + (size_t)(gk + sg1) * 2, As_b + (wid * 2 + 1) * 1024);
        gload16(&wt[(size_t)(bn0 + br0) * N_SZ + gk + sg0], Bs_b + (wid * 2) * 1024);
        gload16(&wt[(size_t)(bn0 + br1) * N_SZ + gk + sg1], Bs_b + (wid * 2 + 1) * 1024);
        __syncthreads();
        f16x8 af[4], bf[4];
        for (int mi = 0; mi < 4; ++mi)
            af[mi] = *reinterpret_cast<const f16x8*>(As_b + (m0 + mi * 16 + rA) * 64 + (cbr ^ rswz));
        for (int ni = 0; ni < 4; ++ni)
            bf[ni] = *reinterpret_cast<const f16x8*>(Bs_b + (n0 + ni * 16 + rA) * 64 + (cbr ^ rswz));
        for (int mi = 0; mi < 4; ++mi)
            for (int ni = 0; ni < 4; ++ni)
                acc[mi][ni] = __builtin_amdgcn_mfma_f32_16x16x32_f16(af[mi], bf[ni], acc[mi][ni], 0, 0, 0);
        __syncthreads();
    }
    for (int mi = 0; mi < 4; ++mi)
        for (int ni = 0; ni < 4; ++ni) {
            const int dd = bn0 + n0 + ni * 16 + rA;
            const int bb = bm0 + m0 + mi * 16 + (lane >> 4) * 4;
            const f32x4 a = acc[mi][ni];
            for (int r = 0; r < 4; ++r)
                Y[(size_t)(bb + r) * D_SZ + dd] = a[r];
        }
}

extern "C" void kernel_launch(void* const* d_in, const int* in_sizes, int n_in,
                              void* d_out, int out_size, void* d_ws, size_t ws_size,
                              hipStream_t stream) {
    (void)in_sizes; (void)n_in; (void)out_size; (void)ws_size;
    const float* X = (const float*)d_in[0];
    const float* W = (const float*)d_in[1];
    float* Y = (float*)d_out;
    char* ws = (char*)d_ws;

    float* L = (float*)ws;                                      // 64 MB (logits + embedded a16)
    _Float16* wh = (_Float16*)(ws + (size_t)64 * 1024 * 1024);  // 1 MB
    _Float16* wt = wh + (size_t)N_SZ * D_SZ;                    // 1 MB
    float* ww = (float*)(wt + (size_t)N_SZ * D_SZ);             // 4 KB

    prep_w<<<N_SZ, 256, 0, stream>>>(W, wh, wt, ww);
    gemm1<<<dim3(N_SZ / 128, B_SZ / 128), 256, 0, stream>>>(X, wh, ww, L);
    softsm<<<B_SZ / 2, 512, 0, stream>>>(L);
    gemm2<<<dim3(D_SZ / 128, B_SZ / 128), 256, 0, stream>>>((const char*)L, wt, Y);
}

// Round 3
// 132.422 us; speedup vs baseline: 1.6435x; 1.1855x over previous
//
#include <hip/hip_runtime.h>
#include <hip/hip_bf16.h>
#include <stdint.h>

#define B_SZ 16384
#define D_SZ 512
#define N_SZ 1024

using f16x8 = __attribute__((ext_vector_type(8))) _Float16;
using f16x4 = __attribute__((ext_vector_type(4))) _Float16;
using f32x4 = __attribute__((ext_vector_type(4))) float;

typedef unsigned int u32_as1 __attribute__((address_space(1)));
typedef unsigned int u32_as3 __attribute__((address_space(3)));

__device__ __forceinline__ void gload16(const void* g, void* lds_base) {
    __builtin_amdgcn_global_load_lds((const u32_as1*)g, (u32_as3*)lds_base, 16, 0, 0);
}

// ---- prep: W -> fp16 plane, fp16 transposed plane, row norms ----
__global__ __launch_bounds__(256) void prep_w(
    const float* __restrict__ W, _Float16* __restrict__ wh,
    _Float16* __restrict__ wt, float* __restrict__ ww) {
    const int n = blockIdx.x;   // 0..1023
    const int t = threadIdx.x;  // 0..255, 2 elements each
    __shared__ float part[4];
    const float2 v = *reinterpret_cast<const float2*>(&W[(size_t)n * D_SZ + t * 2]);
    _Float16 h0 = (_Float16)v.x, h1 = (_Float16)v.y;
    wh[(size_t)n * D_SZ + t * 2] = h0;
    wh[(size_t)n * D_SZ + t * 2 + 1] = h1;
    wt[(size_t)(t * 2) * N_SZ + n] = h0;
    wt[(size_t)(t * 2 + 1) * N_SZ + n] = h1;
    float s = v.x * v.x + v.y * v.y;
    for (int o = 32; o; o >>= 1) s += __shfl_xor(s, o);
    if ((t & 63) == 0) part[t >> 6] = s;
    __syncthreads();
    if (t == 0) ww[n] = part[0] + part[1] + part[2] + part[3];
}

// ---- GEMM1: L[b,n] = 4*(x_b . w_n) - 2*||w_n||^2 ----
__global__ __launch_bounds__(256, 3) void gemm1(
    const float* __restrict__ X, const _Float16* __restrict__ wh,
    const float* __restrict__ ww, float* __restrict__ L) {
    __shared__ _Float16 As[128 * 32];
    __shared__ _Float16 Bs[128 * 32];
    const int tid = threadIdx.x;
    const int wid = tid >> 6, lane = tid & 63;
    const int bn0 = blockIdx.x * 128;
    const int bm0 = blockIdx.y * 128;
    const int m0 = (wid >> 1) * 64, n0 = (wid & 1) * 64;
    const int rA = lane & 15;
    const int cbr = (lane >> 4) * 16;
    const int rswz = ((rA >> 1) & 3) << 4;

    const int ar = tid >> 1;
    const int ac = (tid & 1) * 16;
    const size_t xoff = (size_t)(bm0 + ar) * D_SZ + ac;
    const int aswz = ((ar >> 1) & 3) << 4;
    char* const As_b = (char*)As;
    char* const Bs_b = (char*)Bs;
    char* const aw0 = As_b + ar * 64 + ((ac * 2) ^ aswz);
    char* const aw1 = As_b + ar * 64 + ((ac * 2 + 16) ^ aswz);

    const int br0 = (wid * 2) * 16 + (lane >> 2);
    const int br1 = (wid * 2 + 1) * 16 + (lane >> 2);
    const int sg0 = ((lane & 3) ^ ((br0 >> 1) & 3)) * 8;
    const int sg1 = ((lane & 3) ^ ((br1 >> 1) & 3)) * 8;

    f32x4 acc[4][4];
    for (int mi = 0; mi < 4; ++mi)
        for (int ni = 0; ni < 4; ++ni) acc[mi][ni] = (f32x4){0.f, 0.f, 0.f, 0.f};

    for (int kt = 0; kt < 16; ++kt) {
        const int gk = kt * 32;
        gload16(&wh[(size_t)(bn0 + br0) * D_SZ + gk + sg0], Bs_b + (wid * 2) * 1024);
        gload16(&wh[(size_t)(bn0 + br1) * D_SZ + gk + sg1], Bs_b + (wid * 2 + 1) * 1024);
        const float4 x0 = *reinterpret_cast<const float4*>(&X[xoff + gk]);
        const float4 x1 = *reinterpret_cast<const float4*>(&X[xoff + gk + 4]);
        const float4 x2 = *reinterpret_cast<const float4*>(&X[xoff + gk + 8]);
        const float4 x3 = *reinterpret_cast<const float4*>(&X[xoff + gk + 12]);
        f16x8 h0 = {(_Float16)x0.x, (_Float16)x0.y, (_Float16)x0.z, (_Float16)x0.w,
                    (_Float16)x1.x, (_Float16)x1.y, (_Float16)x1.z, (_Float16)x1.w};
        f16x8 h1 = {(_Float16)x2.x, (_Float16)x2.y, (_Float16)x2.z, (_Float16)x2.w,
                    (_Float16)x3.x, (_Float16)x3.y, (_Float16)x3.z, (_Float16)x3.w};
        *reinterpret_cast<f16x8*>(aw0) = h0;
        *reinterpret_cast<f16x8*>(aw1) = h1;
        __syncthreads();
        f16x8 af[4], bf[4];
        for (int mi = 0; mi < 4; ++mi)
            af[mi] = *reinterpret_cast<const f16x8*>(As_b + (m0 + mi * 16 + rA) * 64 + (cbr ^ rswz));
        for (int ni = 0; ni < 4; ++ni)
            bf[ni] = *reinterpret_cast<const f16x8*>(Bs_b + (n0 + ni * 16 + rA) * 64 + (cbr ^ rswz));
        for (int mi = 0; mi < 4; ++mi)
            for (int ni = 0; ni < 4; ++ni)
                acc[mi][ni] = __builtin_amdgcn_mfma_f32_16x16x32_f16(af[mi], bf[ni], acc[mi][ni], 0, 0, 0);
        __syncthreads();
    }
    for (int mi = 0; mi < 4; ++mi)
        for (int ni = 0; ni < 4; ++ni) {
            const int nn = bn0 + n0 + ni * 16 + rA;
            const float wwn = ww[nn];
            const int bb = bm0 + m0 + mi * 16 + (lane >> 4) * 4;
            const f32x4 a = acc[mi][ni];
            for (int r = 0; r < 4; ++r)
                L[(size_t)(bb + r) * N_SZ + nn] = 4.f * a[r] - 2.f * wwn;
        }
}

// ---- wave-parallel dual-axis softmax; registers only, tiny LDS partials ----
// One block = 256 threads = one L row (32x32 logits). Thread t owns
// (i=t>>3, j=j0..j0+3), j0=(t&7)*4. Row-reduce via shfl 1,2,4 (lane-adjacent
// same-i threads); col-reduce via shfl 8,16,32 in-wave + [4][32] LDS combine.
// Writes fp16 a into second half of the 8KB pair-region:
//   a16 row b at byte 8192*(b>>1) + 4096 + (b&1)*2048.
__global__ __launch_bounds__(256) void softsm(float* __restrict__ L) {
    __shared__ float4 cpart[4][8];
    __shared__ float4 spart[4][8];
    __shared__ float Tp[4];
    const int t = threadIdx.x;
    const int w = t >> 6, lane = t & 63;
    const int g8 = t & 7;  // j-group
    const size_t row = blockIdx.x;
    const float4 v = *reinterpret_cast<const float4*>(&L[row * N_SZ + (size_t)t * 4]);
    float l0 = v.x, l1 = v.y, l2 = v.z, l3 = v.w;

    // row max (over j, fixed i)
    float rm = fmaxf(fmaxf(l0, l1), fmaxf(l2, l3));
    rm = fmaxf(rm, __shfl_xor(rm, 1));
    rm = fmaxf(rm, __shfl_xor(rm, 2));
    rm = fmaxf(rm, __shfl_xor(rm, 4));
    // col max (over i, fixed j): in-wave over 8 i's
    float c0 = l0, c1 = l1, c2 = l2, c3 = l3;
    for (int m = 8; m <= 32; m <<= 1) {
        c0 = fmaxf(c0, __shfl_xor(c0, m));
        c1 = fmaxf(c1, __shfl_xor(c1, m));
        c2 = fmaxf(c2, __shfl_xor(c2, m));
        c3 = fmaxf(c3, __shfl_xor(c3, m));
    }
    if (lane < 8) cpart[w][lane] = make_float4(c0, c1, c2, c3);
    __syncthreads();
    {
        const float4 q0 = cpart[0][g8], q1 = cpart[1][g8], q2 = cpart[2][g8], q3 = cpart[3][g8];
        c0 = fmaxf(fmaxf(q0.x, q1.x), fmaxf(q2.x, q3.x));
        c1 = fmaxf(fmaxf(q0.y, q1.y), fmaxf(q2.y, q3.y));
        c2 = fmaxf(fmaxf(q0.z, q1.z), fmaxf(q2.z, q3.z));
        c3 = fmaxf(fmaxf(q0.w, q1.w), fmaxf(q2.w, q3.w));
    }
    // exp terms
    const float er0 = expf(l0 - rm), er1 = expf(l1 - rm), er2 = expf(l2 - rm), er3 = expf(l3 - rm);
    const float ec0 = expf(l0 - c0), ec1 = expf(l1 - c1), ec2 = expf(l2 - c2), ec3 = expf(l3 - c3);
    // row sum
    float rs = er0 + er1 + er2 + er3;
    rs += __shfl_xor(rs, 1); rs += __shfl_xor(rs, 2); rs += __shfl_xor(rs, 4);
    // col sums
    float s0 = ec0, s1 = ec1, s2 = ec2, s3 = ec3;
    for (int m = 8; m <= 32; m <<= 1) {
        s0 += __shfl_xor(s0, m);
        s1 += __shfl_xor(s1, m);
        s2 += __shfl_xor(s2, m);
        s3 += __shfl_xor(s3, m);
    }
    if (lane < 8) spart[w][lane] = make_float4(s0, s1, s2, s3);
    __syncthreads();
    {
        const float4 q0 = spart[0][g8], q1 = spart[1][g8], q2 = spart[2][g8], q3 = spart[3][g8];
        s0 = (q0.x + q1.x) + (q2.x + q3.x);
        s1 = (q0.y + q1.y) + (q2.y + q3.y);
        s2 = (q0.z + q1.z) + (q2.z + q3.z);
        s3 = (q0.w + q1.w) + (q2.w + q3.w);
    }
    const float irs = 1.f / rs;
    const float tt0 = er0 * ec0 * irs / s0;
    const float tt1 = er1 * ec1 * irs / s1;
    const float tt2 = er2 * ec2 * irs / s2;
    const float tt3 = er3 * ec3 * irs / s3;
    // total renorm
    float sT = (tt0 + tt1) + (tt2 + tt3);
    for (int m = 1; m <= 32; m <<= 1) sT += __shfl_xor(sT, m);
    if (lane == 0) Tp[w] = sT;
    __syncthreads();
    const float T = (Tp[0] + Tp[1]) + (Tp[2] + Tp[3]);
    const float inv = 1.f / (T + 1e-8f);
    f16x4 o = {(_Float16)(tt0 * inv), (_Float16)(tt1 * inv),
               (_Float16)(tt2 * inv), (_Float16)(tt3 * inv)};
    char* out = (char*)L + (row >> 1) * 8192 + 4096 + (row & 1) * 2048 + (size_t)t * 8;
    *reinterpret_cast<f16x4*>(out) = o;
}

// ---- GEMM2: Y[b,d] = sum_n a[b,n] * W[n,d]; both operands via gload_lds ----
__global__ __launch_bounds__(256, 3) void gemm2(
    const char* __restrict__ aBytes, const _Float16* __restrict__ wt,
    float* __restrict__ Y) {
    __shared__ _Float16 As[128 * 32];
    __shared__ _Float16 Bs[128 * 32];
    const int tid = threadIdx.x;
    const int wid = tid >> 6, lane = tid & 63;
    const int bn0 = blockIdx.x * 128;  // d
    const int bm0 = blockIdx.y * 128;  // b
    const int m0 = (wid >> 1) * 64, n0 = (wid & 1) * 64;
    const int rA = lane & 15;
    const int cbr = (lane >> 4) * 16;
    const int rswz = ((rA >> 1) & 3) << 4;

    const int br0 = (wid * 2) * 16 + (lane >> 2);
    const int br1 = (wid * 2 + 1) * 16 + (lane >> 2);
    const int sg0 = ((lane & 3) ^ ((br0 >> 1) & 3)) * 8;
    const int sg1 = ((lane & 3) ^ ((br1 >> 1) & 3)) * 8;
    char* const As_b = (char*)As;
    char* const Bs_b = (char*)Bs;
    const int ab0 = bm0 + br0, ab1 = bm0 + br1;
    const size_t abase0 = (size_t)(ab0 >> 1) * 8192 + 4096 + (size_t)(ab0 & 1) * 2048;
    const size_t abase1 = (size_t)(ab1 >> 1) * 8192 + 4096 + (size_t)(ab1 & 1) * 2048;

    f32x4 acc[4][4];
    for (int mi = 0; mi < 4; ++mi)
        for (int ni = 0; ni < 4; ++ni) acc[mi][ni] = (f32x4){0.f, 0.f, 0.f, 0.f};

    for (int kt = 0; kt < 32; ++kt) {
        const int gk = kt * 32;
        gload16(aBytes + abase0 + (size_t)(gk + sg0) * 2, As_b + (wid * 2) * 1024);
        gload16(aBytes + abase1 + (size_t)(gk + sg1) * 2, As_b + (wid * 2 + 1) * 1024);
        gload16(&wt[(size_t)(bn0 + br0) * N_SZ + gk + sg0], Bs_b + (wid * 2) * 1024);
        gload16(&wt[(size_t)(bn0 + br1) * N_SZ + gk + sg1], Bs_b + (wid * 2 + 1) * 1024);
        __syncthreads();
        f16x8 af[4], bf[4];
        for (int mi = 0; mi < 4; ++mi)
            af[mi] = *reinterpret_cast<const f16x8*>(As_b + (m0 + mi * 16 + rA) * 64 + (cbr ^ rswz));
        for (int ni = 0; ni < 4; ++ni)
            bf[ni] = *reinterpret_cast<const f16x8*>(Bs_b + (n0 + ni * 16 + rA) * 64 + (cbr ^ rswz));
        for (int mi = 0; mi < 4; ++mi)
            for (int ni = 0; ni < 4; ++ni)
                acc[mi][ni] = __builtin_amdgcn_mfma_f32_16x16x32_f16(af[mi], bf[ni], acc[mi][ni], 0, 0, 0);
        __syncthreads();
    }
    for (int mi = 0; mi < 4; ++mi)
        for (int ni = 0; ni < 4; ++ni) {
            const int dd = bn0 + n0 + ni * 16 + rA;
            const int bb = bm0 + m0 + mi * 16 + (lane >> 4) * 4;
            const f32x4 a = acc[mi][ni];
            for (int r = 0; r < 4; ++r)
                Y[(size_t)(bb + r) * D_SZ + dd] = a[r];
        }
}

extern "C" void kernel_launch(void* const* d_in, const int* in_sizes, int n_in,
                              void* d_out, int out_size, void* d_ws, size_t ws_size,
                              hipStream_t stream) {
    (void)in_sizes; (void)n_in; (void)out_size; (void)ws_size;
    const float* X = (const float*)d_in[0];
    const float* W = (const float*)d_in[1];
    float* Y = (float*)d_out;
    char* ws = (char*)d_ws;

    float* L = (float*)ws;                                      // 64 MB (logits + embedded a16)
    _Float16* wh = (_Float16*)(ws + (size_t)64 * 1024 * 1024);  // 1 MB
    _Float16* wt = wh + (size_t)N_SZ * D_SZ;                    // 1 MB
    float* ww = (float*)(wt + (size_t)N_SZ * D_SZ);             // 4 KB

    prep_w<<<N_SZ, 256, 0, stream>>>(W, wh, wt, ww);
    gemm1<<<dim3(N_SZ / 128, B_SZ / 128), 256, 0, stream>>>(X, wh, ww, L);
    softsm<<<B_SZ, 256, 0, stream>>>(L);
    gemm2<<<dim3(D_SZ / 128, B_SZ / 128), 256, 0, stream>>>((const char*)L, wt, Y);
}

// Round 4
// 114.361 us; speedup vs baseline: 1.9030x; 1.1579x over previous
//
#include <hip/hip_runtime.h>
#include <hip/hip_bf16.h>
#include <stdint.h>

#define B_SZ 16384
#define D_SZ 512
#define N_SZ 1024

using f16x8 = __attribute__((ext_vector_type(8))) _Float16;
using f16x4 = __attribute__((ext_vector_type(4))) _Float16;
using f32x4 = __attribute__((ext_vector_type(4))) float;

typedef unsigned int u32_as1 __attribute__((address_space(1)));
typedef unsigned int u32_as3 __attribute__((address_space(3)));

__device__ __forceinline__ void gload16(const void* g, void* lds_base) {
    __builtin_amdgcn_global_load_lds((const u32_as1*)g, (u32_as3*)lds_base, 16, 0, 0);
}

// ---- prep: W -> fp16 plane, fp16 transposed plane, row norms ----
__global__ __launch_bounds__(256) void prep_w(
    const float* __restrict__ W, _Float16* __restrict__ wh,
    _Float16* __restrict__ wt, float* __restrict__ ww) {
    const int n = blockIdx.x;
    const int t = threadIdx.x;
    __shared__ float part[4];
    const float2 v = *reinterpret_cast<const float2*>(&W[(size_t)n * D_SZ + t * 2]);
    _Float16 h0 = (_Float16)v.x, h1 = (_Float16)v.y;
    wh[(size_t)n * D_SZ + t * 2] = h0;
    wh[(size_t)n * D_SZ + t * 2 + 1] = h1;
    wt[(size_t)(t * 2) * N_SZ + n] = h0;
    wt[(size_t)(t * 2 + 1) * N_SZ + n] = h1;
    float s = v.x * v.x + v.y * v.y;
    for (int o = 32; o; o >>= 1) s += __shfl_xor(s, o);
    if ((t & 63) == 0) part[t >> 6] = s;
    __syncthreads();
    if (t == 0) ww[n] = part[0] + part[1] + part[2] + part[3];
}

// ---- GEMM1: L[b,n] = 4*(x_b . w_n) - 2*||w_n||^2 ----
// 2-phase double-buffered: issue tile k+1 loads before computing tile k.
// XCD-contiguous block remap: each XCD gets 16 consecutive b-tiles.
__global__ __launch_bounds__(256, 2) void gemm1(
    const float* __restrict__ X, const _Float16* __restrict__ wh,
    const float* __restrict__ ww, float* __restrict__ L) {
    __shared__ _Float16 As[2 * 128 * 32];
    __shared__ _Float16 Bs[2 * 128 * 32];
    const int tid = threadIdx.x;
    const int wid = tid >> 6, lane = tid & 63;
    const int raw = blockIdx.y * 8 + blockIdx.x;          // 0..1023
    const int wsw = (raw & 7) * 128 + (raw >> 3);         // bijective XCD chunking
    const int bn0 = (wsw & 7) * 128;
    const int bm0 = (wsw >> 3) * 128;
    const int m0 = (wid >> 1) * 64, n0 = (wid & 1) * 64;
    const int rA = lane & 15;
    const int cbr = (lane >> 4) * 16;
    const int rswz = ((rA >> 1) & 3) << 4;

    // A staging geometry
    const int ar = tid >> 1;
    const int ac = (tid & 1) * 16;
    const size_t xoff = (size_t)(bm0 + ar) * D_SZ + ac;
    const int aswz = ((ar >> 1) & 3) << 4;
    const int awo0 = ar * 64 + ((ac * 2) ^ aswz);
    const int awo1 = ar * 64 + ((ac * 2 + 16) ^ aswz);
    char* const As_b = (char*)As;
    char* const Bs_b = (char*)Bs;

    // B staging geometry
    const int br0 = (wid * 2) * 16 + (lane >> 2);
    const int br1 = (wid * 2 + 1) * 16 + (lane >> 2);
    const int sg0 = ((lane & 3) ^ ((br0 >> 1) & 3)) * 8;
    const int sg1 = ((lane & 3) ^ ((br1 >> 1) & 3)) * 8;
    const int bdst0 = (wid * 2) * 1024;
    const int bdst1 = (wid * 2 + 1) * 1024;

    f32x4 acc[4][4];
    for (int mi = 0; mi < 4; ++mi)
        for (int ni = 0; ni < 4; ++ni) acc[mi][ni] = (f32x4){0.f, 0.f, 0.f, 0.f};

    // ---- prologue: stage tile 0 into buffer 0 ----
    {
        const float4 x0 = *reinterpret_cast<const float4*>(&X[xoff]);
        const float4 x1 = *reinterpret_cast<const float4*>(&X[xoff + 4]);
        const float4 x2 = *reinterpret_cast<const float4*>(&X[xoff + 8]);
        const float4 x3 = *reinterpret_cast<const float4*>(&X[xoff + 12]);
        gload16(&wh[(size_t)(bn0 + br0) * D_SZ + sg0], Bs_b + bdst0);
        gload16(&wh[(size_t)(bn0 + br1) * D_SZ + sg1], Bs_b + bdst1);
        f16x8 h0 = {(_Float16)x0.x, (_Float16)x0.y, (_Float16)x0.z, (_Float16)x0.w,
                    (_Float16)x1.x, (_Float16)x1.y, (_Float16)x1.z, (_Float16)x1.w};
        f16x8 h1 = {(_Float16)x2.x, (_Float16)x2.y, (_Float16)x2.z, (_Float16)x2.w,
                    (_Float16)x3.x, (_Float16)x3.y, (_Float16)x3.z, (_Float16)x3.w};
        *reinterpret_cast<f16x8*>(As_b + awo0) = h0;
        *reinterpret_cast<f16x8*>(As_b + awo1) = h1;
    }
    __syncthreads();

    int cur = 0;
    for (int kt = 0; kt < 16; ++kt) {
        const int nxt = cur ^ 1;
        float4 x0, x1, x2, x3;
        if (kt < 15) {
            const int gk = (kt + 1) * 32;
            // issue next-tile loads first (X vmem, then B gload_lds)
            x0 = *reinterpret_cast<const float4*>(&X[xoff + gk]);
            x1 = *reinterpret_cast<const float4*>(&X[xoff + gk + 4]);
            x2 = *reinterpret_cast<const float4*>(&X[xoff + gk + 8]);
            x3 = *reinterpret_cast<const float4*>(&X[xoff + gk + 12]);
            gload16(&wh[(size_t)(bn0 + br0) * D_SZ + gk + sg0], Bs_b + nxt * 8192 + bdst0);
            gload16(&wh[(size_t)(bn0 + br1) * D_SZ + gk + sg1], Bs_b + nxt * 8192 + bdst1);
        }
        // compute current tile
        f16x8 af[4], bf[4];
        for (int mi = 0; mi < 4; ++mi)
            af[mi] = *reinterpret_cast<const f16x8*>(
                As_b + cur * 8192 + (m0 + mi * 16 + rA) * 64 + (cbr ^ rswz));
        for (int ni = 0; ni < 4; ++ni)
            bf[ni] = *reinterpret_cast<const f16x8*>(
                Bs_b + cur * 8192 + (n0 + ni * 16 + rA) * 64 + (cbr ^ rswz));
        for (int mi = 0; mi < 4; ++mi)
            for (int ni = 0; ni < 4; ++ni)
                acc[mi][ni] = __builtin_amdgcn_mfma_f32_16x16x32_f16(af[mi], bf[ni], acc[mi][ni], 0, 0, 0);
        if (kt < 15) {
            f16x8 h0 = {(_Float16)x0.x, (_Float16)x0.y, (_Float16)x0.z, (_Float16)x0.w,
                        (_Float16)x1.x, (_Float16)x1.y, (_Float16)x1.z, (_Float16)x1.w};
            f16x8 h1 = {(_Float16)x2.x, (_Float16)x2.y, (_Float16)x2.z, (_Float16)x2.w,
                        (_Float16)x3.x, (_Float16)x3.y, (_Float16)x3.z, (_Float16)x3.w};
            *reinterpret_cast<f16x8*>(As_b + nxt * 8192 + awo0) = h0;
            *reinterpret_cast<f16x8*>(As_b + nxt * 8192 + awo1) = h1;
        }
        __syncthreads();
        cur = nxt;
    }
    for (int mi = 0; mi < 4; ++mi)
        for (int ni = 0; ni < 4; ++ni) {
            const int nn = bn0 + n0 + ni * 16 + rA;
            const float wwn = ww[nn];
            const int bb = bm0 + m0 + mi * 16 + (lane >> 4) * 4;
            const f32x4 a = acc[mi][ni];
            for (int r = 0; r < 4; ++r)
                L[(size_t)(bb + r) * N_SZ + nn] = 4.f * a[r] - 2.f * wwn;
        }
}

// ---- wave-parallel dual-axis softmax (unchanged from R3) ----
__global__ __launch_bounds__(256) void softsm(float* __restrict__ L) {
    __shared__ float4 cpart[4][8];
    __shared__ float4 spart[4][8];
    __shared__ float Tp[4];
    const int t = threadIdx.x;
    const int w = t >> 6, lane = t & 63;
    const int g8 = t & 7;
    const size_t row = blockIdx.x;
    const float4 v = *reinterpret_cast<const float4*>(&L[row * N_SZ + (size_t)t * 4]);
    float l0 = v.x, l1 = v.y, l2 = v.z, l3 = v.w;

    float rm = fmaxf(fmaxf(l0, l1), fmaxf(l2, l3));
    rm = fmaxf(rm, __shfl_xor(rm, 1));
    rm = fmaxf(rm, __shfl_xor(rm, 2));
    rm = fmaxf(rm, __shfl_xor(rm, 4));
    float c0 = l0, c1 = l1, c2 = l2, c3 = l3;
    for (int m = 8; m <= 32; m <<= 1) {
        c0 = fmaxf(c0, __shfl_xor(c0, m));
        c1 = fmaxf(c1, __shfl_xor(c1, m));
        c2 = fmaxf(c2, __shfl_xor(c2, m));
        c3 = fmaxf(c3, __shfl_xor(c3, m));
    }
    if (lane < 8) cpart[w][lane] = make_float4(c0, c1, c2, c3);
    __syncthreads();
    {
        const float4 q0 = cpart[0][g8], q1 = cpart[1][g8], q2 = cpart[2][g8], q3 = cpart[3][g8];
        c0 = fmaxf(fmaxf(q0.x, q1.x), fmaxf(q2.x, q3.x));
        c1 = fmaxf(fmaxf(q0.y, q1.y), fmaxf(q2.y, q3.y));
        c2 = fmaxf(fmaxf(q0.z, q1.z), fmaxf(q2.z, q3.z));
        c3 = fmaxf(fmaxf(q0.w, q1.w), fmaxf(q2.w, q3.w));
    }
    const float er0 = expf(l0 - rm), er1 = expf(l1 - rm), er2 = expf(l2 - rm), er3 = expf(l3 - rm);
    const float ec0 = expf(l0 - c0), ec1 = expf(l1 - c1), ec2 = expf(l2 - c2), ec3 = expf(l3 - c3);
    float rs = er0 + er1 + er2 + er3;
    rs += __shfl_xor(rs, 1); rs += __shfl_xor(rs, 2); rs += __shfl_xor(rs, 4);
    float s0 = ec0, s1 = ec1, s2 = ec2, s3 = ec3;
    for (int m = 8; m <= 32; m <<= 1) {
        s0 += __shfl_xor(s0, m);
        s1 += __shfl_xor(s1, m);
        s2 += __shfl_xor(s2, m);
        s3 += __shfl_xor(s3, m);
    }
    if (lane < 8) spart[w][lane] = make_float4(s0, s1, s2, s3);
    __syncthreads();
    {
        const float4 q0 = spart[0][g8], q1 = spart[1][g8], q2 = spart[2][g8], q3 = spart[3][g8];
        s0 = (q0.x + q1.x) + (q2.x + q3.x);
        s1 = (q0.y + q1.y) + (q2.y + q3.y);
        s2 = (q0.z + q1.z) + (q2.z + q3.z);
        s3 = (q0.w + q1.w) + (q2.w + q3.w);
    }
    const float irs = 1.f / rs;
    const float tt0 = er0 * ec0 * irs / s0;
    const float tt1 = er1 * ec1 * irs / s1;
    const float tt2 = er2 * ec2 * irs / s2;
    const float tt3 = er3 * ec3 * irs / s3;
    float sT = (tt0 + tt1) + (tt2 + tt3);
    for (int m = 1; m <= 32; m <<= 1) sT += __shfl_xor(sT, m);
    if (lane == 0) Tp[w] = sT;
    __syncthreads();
    const float T = (Tp[0] + Tp[1]) + (Tp[2] + Tp[3]);
    const float inv = 1.f / (T + 1e-8f);
    f16x4 o = {(_Float16)(tt0 * inv), (_Float16)(tt1 * inv),
               (_Float16)(tt2 * inv), (_Float16)(tt3 * inv)};
    char* out = (char*)L + (row >> 1) * 8192 + 4096 + (row & 1) * 2048 + (size_t)t * 8;
    *reinterpret_cast<f16x4*>(out) = o;
}

// ---- GEMM2: Y[b,d] = sum_n a[b,n] * W[n,d]; 2-phase, all gload_lds ----
__global__ __launch_bounds__(256, 2) void gemm2(
    const char* __restrict__ aBytes, const _Float16* __restrict__ wt,
    float* __restrict__ Y) {
    __shared__ _Float16 As[2 * 128 * 32];
    __shared__ _Float16 Bs[2 * 128 * 32];
    const int tid = threadIdx.x;
    const int wid = tid >> 6, lane = tid & 63;
    const int raw = blockIdx.y * 4 + blockIdx.x;          // 0..511
    const int wsw = (raw & 7) * 64 + (raw >> 3);          // bijective XCD chunking
    const int bn0 = (wsw & 3) * 128;  // d
    const int bm0 = (wsw >> 2) * 128; // b
    const int m0 = (wid >> 1) * 64, n0 = (wid & 1) * 64;
    const int rA = lane & 15;
    const int cbr = (lane >> 4) * 16;
    const int rswz = ((rA >> 1) & 3) << 4;

    const int br0 = (wid * 2) * 16 + (lane >> 2);
    const int br1 = (wid * 2 + 1) * 16 + (lane >> 2);
    const int sg0 = ((lane & 3) ^ ((br0 >> 1) & 3)) * 8;
    const int sg1 = ((lane & 3) ^ ((br1 >> 1) & 3)) * 8;
    const int bdst0 = (wid * 2) * 1024;
    const int bdst1 = (wid * 2 + 1) * 1024;
    char* const As_b = (char*)As;
    char* const Bs_b = (char*)Bs;
    const int ab0 = bm0 + br0, ab1 = bm0 + br1;
    const size_t abase0 = (size_t)(ab0 >> 1) * 8192 + 4096 + (size_t)(ab0 & 1) * 2048;
    const size_t abase1 = (size_t)(ab1 >> 1) * 8192 + 4096 + (size_t)(ab1 & 1) * 2048;

    f32x4 acc[4][4];
    for (int mi = 0; mi < 4; ++mi)
        for (int ni = 0; ni < 4; ++ni) acc[mi][ni] = (f32x4){0.f, 0.f, 0.f, 0.f};

    // prologue: stage tile 0 into buffer 0
    gload16(aBytes + abase0 + (size_t)sg0 * 2, As_b + bdst0);
    gload16(aBytes + abase1 + (size_t)sg1 * 2, As_b + bdst1);
    gload16(&wt[(size_t)(bn0 + br0) * N_SZ + sg0], Bs_b + bdst0);
    gload16(&wt[(size_t)(bn0 + br1) * N_SZ + sg1], Bs_b + bdst1);
    __syncthreads();

    int cur = 0;
    for (int kt = 0; kt < 32; ++kt) {
        const int nxt = cur ^ 1;
        if (kt < 31) {
            const int gk = (kt + 1) * 32;
            gload16(aBytes + abase0 + (size_t)(gk + sg0) * 2, As_b + nxt * 8192 + bdst0);
            gload16(aBytes + abase1 + (size_t)(gk + sg1) * 2, As_b + nxt * 8192 + bdst1);
            gload16(&wt[(size_t)(bn0 + br0) * N_SZ + gk + sg0], Bs_b + nxt * 8192 + bdst0);
            gload16(&wt[(size_t)(bn0 + br1) * N_SZ + gk + sg1], Bs_b + nxt * 8192 + bdst1);
        }
        f16x8 af[4], bf[4];
        for (int mi = 0; mi < 4; ++mi)
            af[mi] = *reinterpret_cast<const f16x8*>(
                As_b + cur * 8192 + (m0 + mi * 16 + rA) * 64 + (cbr ^ rswz));
        for (int ni = 0; ni < 4; ++ni)
            bf[ni] = *reinterpret_cast<const f16x8*>(
                Bs_b + cur * 8192 + (n0 + ni * 16 + rA) * 64 + (cbr ^ rswz));
        for (int mi = 0; mi < 4; ++mi)
            for (int ni = 0; ni < 4; ++ni)
                acc[mi][ni] = __builtin_amdgcn_mfma_f32_16x16x32_f16(af[mi], bf[ni], acc[mi][ni], 0, 0, 0);
        __syncthreads();
        cur = nxt;
    }
    for (int mi = 0; mi < 4; ++mi)
        for (int ni = 0; ni < 4; ++ni) {
            const int dd = bn0 + n0 + ni * 16 + rA;
            const int bb = bm0 + m0 + mi * 16 + (lane >> 4) * 4;
            const f32x4 a = acc[mi][ni];
            for (int r = 0; r < 4; ++r)
                Y[(size_t)(bb + r) * D_SZ + dd] = a[r];
        }
}

extern "C" void kernel_launch(void* const* d_in, const int* in_sizes, int n_in,
                              void* d_out, int out_size, void* d_ws, size_t ws_size,
                              hipStream_t stream) {
    (void)in_sizes; (void)n_in; (void)out_size; (void)ws_size;
    const float* X = (const float*)d_in[0];
    const float* W = (const float*)d_in[1];
    float* Y = (float*)d_out;
    char* ws = (char*)d_ws;

    float* L = (float*)ws;                                      // 64 MB (logits + embedded a16)
    _Float16* wh = (_Float16*)(ws + (size_t)64 * 1024 * 1024);  // 1 MB
    _Float16* wt = wh + (size_t)N_SZ * D_SZ;                    // 1 MB
    float* ww = (float*)(wt + (size_t)N_SZ * D_SZ);             // 4 KB

    prep_w<<<N_SZ, 256, 0, stream>>>(W, wh, wt, ww);
    gemm1<<<dim3(N_SZ / 128, B_SZ / 128), 256, 0, stream>>>(X, wh, ww, L);
    softsm<<<B_SZ, 256, 0, stream>>>(L);
    gemm2<<<dim3(D_SZ / 128, B_SZ / 128), 256, 0, stream>>>((const char*)L, wt, Y);
}

// Round 5
// 105.494 us; speedup vs baseline: 2.0630x; 1.0841x over previous
//
#include <hip/hip_runtime.h>
#include <hip/hip_bf16.h>
#include <stdint.h>

#define B_SZ 16384
#define D_SZ 512
#define N_SZ 1024

using f16x8 = __attribute__((ext_vector_type(8))) _Float16;
using f16x4 = __attribute__((ext_vector_type(4))) _Float16;
using f32x4 = __attribute__((ext_vector_type(4))) float;

typedef unsigned int u32_as1 __attribute__((address_space(1)));
typedef unsigned int u32_as3 __attribute__((address_space(3)));

__device__ __forceinline__ void gload16(const void* g, void* lds_base) {
    __builtin_amdgcn_global_load_lds((const u32_as1*)g, (u32_as3*)lds_base, 16, 0, 0);
}

// ---- prep: W -> fp16 plane, fp16 transposed plane, row norms ----
__global__ __launch_bounds__(256) void prep_w(
    const float* __restrict__ W, _Float16* __restrict__ wh,
    _Float16* __restrict__ wt, float* __restrict__ ww) {
    const int n = blockIdx.x;
    const int t = threadIdx.x;
    __shared__ float part[4];
    const float2 v = *reinterpret_cast<const float2*>(&W[(size_t)n * D_SZ + t * 2]);
    _Float16 h0 = (_Float16)v.x, h1 = (_Float16)v.y;
    wh[(size_t)n * D_SZ + t * 2] = h0;
    wh[(size_t)n * D_SZ + t * 2 + 1] = h1;
    wt[(size_t)(t * 2) * N_SZ + n] = h0;
    wt[(size_t)(t * 2 + 1) * N_SZ + n] = h1;
    float s = v.x * v.x + v.y * v.y;
    for (int o = 32; o; o >>= 1) s += __shfl_xor(s, o);
    if ((t & 63) == 0) part[t >> 6] = s;
    __syncthreads();
    if (t == 0) ww[n] = part[0] + part[1] + part[2] + part[3];
}

// ---- prep: X f32 -> fp16 plane (one streaming pass) ----
__global__ __launch_bounds__(256) void prep_x(
    const float* __restrict__ X, _Float16* __restrict__ xh) {
    const size_t idx = ((size_t)blockIdx.x * 256 + threadIdx.x) * 8;
    const float4 a = *reinterpret_cast<const float4*>(&X[idx]);
    const float4 b = *reinterpret_cast<const float4*>(&X[idx + 4]);
    f16x8 h = {(_Float16)a.x, (_Float16)a.y, (_Float16)a.z, (_Float16)a.w,
               (_Float16)b.x, (_Float16)b.y, (_Float16)b.z, (_Float16)b.w};
    *reinterpret_cast<f16x8*>(&xh[idx]) = h;
}

// ---- GEMM1: L[b,n] = 4*(x_b . w_n) - 2*||w_n||^2; all-gload_lds 2-phase ----
__global__ __launch_bounds__(256, 3) void gemm1(
    const _Float16* __restrict__ xh, const _Float16* __restrict__ wh,
    const float* __restrict__ ww, float* __restrict__ L) {
    __shared__ _Float16 As[2 * 128 * 32];
    __shared__ _Float16 Bs[2 * 128 * 32];
    const int tid = threadIdx.x;
    const int wid = tid >> 6, lane = tid & 63;
    const int raw = blockIdx.y * 8 + blockIdx.x;          // 0..1023
    const int wsw = (raw & 7) * 128 + (raw >> 3);         // bijective XCD chunking
    const int bn0 = (wsw & 7) * 128;
    const int bm0 = (wsw >> 3) * 128;
    const int m0 = (wid >> 1) * 64, n0 = (wid & 1) * 64;
    const int rA = lane & 15;
    const int cbr = (lane >> 4) * 16;
    const int rswz = ((rA >> 1) & 3) << 4;

    const int br0 = (wid * 2) * 16 + (lane >> 2);
    const int br1 = (wid * 2 + 1) * 16 + (lane >> 2);
    const int sg0 = ((lane & 3) ^ ((br0 >> 1) & 3)) * 8;
    const int sg1 = ((lane & 3) ^ ((br1 >> 1) & 3)) * 8;
    const int bdst0 = (wid * 2) * 1024;
    const int bdst1 = (wid * 2 + 1) * 1024;
    char* const As_b = (char*)As;
    char* const Bs_b = (char*)Bs;

    f32x4 acc[4][4];
    for (int mi = 0; mi < 4; ++mi)
        for (int ni = 0; ni < 4; ++ni) acc[mi][ni] = (f32x4){0.f, 0.f, 0.f, 0.f};

    // prologue: stage tile 0 into buffer 0
    gload16(&xh[(size_t)(bm0 + br0) * D_SZ + sg0], As_b + bdst0);
    gload16(&xh[(size_t)(bm0 + br1) * D_SZ + sg1], As_b + bdst1);
    gload16(&wh[(size_t)(bn0 + br0) * D_SZ + sg0], Bs_b + bdst0);
    gload16(&wh[(size_t)(bn0 + br1) * D_SZ + sg1], Bs_b + bdst1);
    __syncthreads();

    int cur = 0;
    for (int kt = 0; kt < 16; ++kt) {
        const int nxt = cur ^ 1;
        if (kt < 15) {
            const int gk = (kt + 1) * 32;
            gload16(&xh[(size_t)(bm0 + br0) * D_SZ + gk + sg0], As_b + nxt * 8192 + bdst0);
            gload16(&xh[(size_t)(bm0 + br1) * D_SZ + gk + sg1], As_b + nxt * 8192 + bdst1);
            gload16(&wh[(size_t)(bn0 + br0) * D_SZ + gk + sg0], Bs_b + nxt * 8192 + bdst0);
            gload16(&wh[(size_t)(bn0 + br1) * D_SZ + gk + sg1], Bs_b + nxt * 8192 + bdst1);
        }
        f16x8 af[4], bf[4];
        for (int mi = 0; mi < 4; ++mi)
            af[mi] = *reinterpret_cast<const f16x8*>(
                As_b + cur * 8192 + (m0 + mi * 16 + rA) * 64 + (cbr ^ rswz));
        for (int ni = 0; ni < 4; ++ni)
            bf[ni] = *reinterpret_cast<const f16x8*>(
                Bs_b + cur * 8192 + (n0 + ni * 16 + rA) * 64 + (cbr ^ rswz));
        for (int mi = 0; mi < 4; ++mi)
            for (int ni = 0; ni < 4; ++ni)
                acc[mi][ni] = __builtin_amdgcn_mfma_f32_16x16x32_f16(af[mi], bf[ni], acc[mi][ni], 0, 0, 0);
        __syncthreads();
        cur = nxt;
    }
    for (int mi = 0; mi < 4; ++mi)
        for (int ni = 0; ni < 4; ++ni) {
            const int nn = bn0 + n0 + ni * 16 + rA;
            const float wwn = ww[nn];
            const int bb = bm0 + m0 + mi * 16 + (lane >> 4) * 4;
            const f32x4 a = acc[mi][ni];
            for (int r = 0; r < 4; ++r)
                L[(size_t)(bb + r) * N_SZ + nn] = 4.f * a[r] - 2.f * wwn;
        }
}

// ---- wave-parallel dual-axis softmax, single global shift, native exp/rcp ----
// softmax over axis k is shift-invariant, so one global max M serves both:
// u = exp(l-M); s_rows*s_cols = u^2 / (rowsum(u)*colsum(u)).
// Block->row map puts row r on XCD r>>11 (matches gemm1's L write locality).
__global__ __launch_bounds__(256) void softsm(float* __restrict__ L) {
    __shared__ float4 spart[4][8];
    __shared__ float mpart[4];
    __shared__ float Tp[4];
    const int t = threadIdx.x;
    const int w = t >> 6, lane = t & 63;
    const int g8 = t & 7;
    const int bid = blockIdx.x;
    const size_t row = (size_t)((bid & 7) * 2048 + (bid >> 3));
    const float4 v = *reinterpret_cast<const float4*>(&L[row * N_SZ + (size_t)t * 4]);

    float m = fmaxf(fmaxf(v.x, v.y), fmaxf(v.z, v.w));
    for (int o = 32; o; o >>= 1) m = fmaxf(m, __shfl_xor(m, o));
    if (lane == 0) mpart[w] = m;
    __syncthreads();
    m = fmaxf(fmaxf(mpart[0], mpart[1]), fmaxf(mpart[2], mpart[3]));

    const float u0 = __expf(v.x - m), u1 = __expf(v.y - m);
    const float u2 = __expf(v.z - m), u3 = __expf(v.w - m);
    // row sum (over j): 8 lanes hold the full row for fixed i
    float rs = (u0 + u1) + (u2 + u3);
    rs += __shfl_xor(rs, 1); rs += __shfl_xor(rs, 2); rs += __shfl_xor(rs, 4);
    // col sums (over i): stride-8 lanes + cross-wave combine
    float s0 = u0, s1 = u1, s2 = u2, s3 = u3;
    for (int o = 8; o <= 32; o <<= 1) {
        s0 += __shfl_xor(s0, o); s1 += __shfl_xor(s1, o);
        s2 += __shfl_xor(s2, o); s3 += __shfl_xor(s3, o);
    }
    if (lane < 8) spart[w][lane] = make_float4(s0, s1, s2, s3);
    __syncthreads();
    {
        const float4 q0 = spart[0][g8], q1 = spart[1][g8], q2 = spart[2][g8], q3 = spart[3][g8];
        s0 = (q0.x + q1.x) + (q2.x + q3.x);
        s1 = (q0.y + q1.y) + (q2.y + q3.y);
        s2 = (q0.z + q1.z) + (q2.z + q3.z);
        s3 = (q0.w + q1.w) + (q2.w + q3.w);
    }
    const float irs = __builtin_amdgcn_rcpf(rs);
    const float t0 = u0 * u0 * irs * __builtin_amdgcn_rcpf(s0);
    const float t1 = u1 * u1 * irs * __builtin_amdgcn_rcpf(s1);
    const float t2 = u2 * u2 * irs * __builtin_amdgcn_rcpf(s2);
    const float t3 = u3 * u3 * irs * __builtin_amdgcn_rcpf(s3);
    float sT = (t0 + t1) + (t2 + t3);
    for (int o = 1; o <= 32; o <<= 1) sT += __shfl_xor(sT, o);
    if (lane == 0) Tp[w] = sT;
    __syncthreads();
    const float T = (Tp[0] + Tp[1]) + (Tp[2] + Tp[3]);
    const float inv = __builtin_amdgcn_rcpf(T + 1e-8f);
    f16x4 o16 = {(_Float16)(t0 * inv), (_Float16)(t1 * inv),
                 (_Float16)(t2 * inv), (_Float16)(t3 * inv)};
    char* out = (char*)L + (row >> 1) * 8192 + 4096 + (row & 1) * 2048 + (size_t)t * 8;
    *reinterpret_cast<f16x4*>(out) = o16;
}

// ---- GEMM2: Y[b,d] = sum_n a[b,n] * W[n,d]; 2-phase, all gload_lds ----
__global__ __launch_bounds__(256, 3) void gemm2(
    const char* __restrict__ aBytes, const _Float16* __restrict__ wt,
    float* __restrict__ Y) {
    __shared__ _Float16 As[2 * 128 * 32];
    __shared__ _Float16 Bs[2 * 128 * 32];
    const int tid = threadIdx.x;
    const int wid = tid >> 6, lane = tid & 63;
    const int raw = blockIdx.y * 4 + blockIdx.x;          // 0..511
    const int wsw = (raw & 7) * 64 + (raw >> 3);          // bijective XCD chunking
    const int bn0 = (wsw & 3) * 128;  // d
    const int bm0 = (wsw >> 2) * 128; // b
    const int m0 = (wid >> 1) * 64, n0 = (wid & 1) * 64;
    const int rA = lane & 15;
    const int cbr = (lane >> 4) * 16;
    const int rswz = ((rA >> 1) & 3) << 4;

    const int br0 = (wid * 2) * 16 + (lane >> 2);
    const int br1 = (wid * 2 + 1) * 16 + (lane >> 2);
    const int sg0 = ((lane & 3) ^ ((br0 >> 1) & 3)) * 8;
    const int sg1 = ((lane & 3) ^ ((br1 >> 1) & 3)) * 8;
    const int bdst0 = (wid * 2) * 1024;
    const int bdst1 = (wid * 2 + 1) * 1024;
    char* const As_b = (char*)As;
    char* const Bs_b = (char*)Bs;
    const int ab0 = bm0 + br0, ab1 = bm0 + br1;
    const size_t abase0 = (size_t)(ab0 >> 1) * 8192 + 4096 + (size_t)(ab0 & 1) * 2048;
    const size_t abase1 = (size_t)(ab1 >> 1) * 8192 + 4096 + (size_t)(ab1 & 1) * 2048;

    f32x4 acc[4][4];
    for (int mi = 0; mi < 4; ++mi)
        for (int ni = 0; ni < 4; ++ni) acc[mi][ni] = (f32x4){0.f, 0.f, 0.f, 0.f};

    gload16(aBytes + abase0 + (size_t)sg0 * 2, As_b + bdst0);
    gload16(aBytes + abase1 + (size_t)sg1 * 2, As_b + bdst1);
    gload16(&wt[(size_t)(bn0 + br0) * N_SZ + sg0], Bs_b + bdst0);
    gload16(&wt[(size_t)(bn0 + br1) * N_SZ + sg1], Bs_b + bdst1);
    __syncthreads();

    int cur = 0;
    for (int kt = 0; kt < 32; ++kt) {
        const int nxt = cur ^ 1;
        if (kt < 31) {
            const int gk = (kt + 1) * 32;
            gload16(aBytes + abase0 + (size_t)(gk + sg0) * 2, As_b + nxt * 8192 + bdst0);
            gload16(aBytes + abase1 + (size_t)(gk + sg1) * 2, As_b + nxt * 8192 + bdst1);
            gload16(&wt[(size_t)(bn0 + br0) * N_SZ + gk + sg0], Bs_b + nxt * 8192 + bdst0);
            gload16(&wt[(size_t)(bn0 + br1) * N_SZ + gk + sg1], Bs_b + nxt * 8192 + bdst1);
        }
        f16x8 af[4], bf[4];
        for (int mi = 0; mi < 4; ++mi)
            af[mi] = *reinterpret_cast<const f16x8*>(
                As_b + cur * 8192 + (m0 + mi * 16 + rA) * 64 + (cbr ^ rswz));
        for (int ni = 0; ni < 4; ++ni)
            bf[ni] = *reinterpret_cast<const f16x8*>(
                Bs_b + cur * 8192 + (n0 + ni * 16 + rA) * 64 + (cbr ^ rswz));
        for (int mi = 0; mi < 4; ++mi)
            for (int ni = 0; ni < 4; ++ni)
                acc[mi][ni] = __builtin_amdgcn_mfma_f32_16x16x32_f16(af[mi], bf[ni], acc[mi][ni], 0, 0, 0);
        __syncthreads();
        cur = nxt;
    }
    for (int mi = 0; mi < 4; ++mi)
        for (int ni = 0; ni < 4; ++ni) {
            const int dd = bn0 + n0 + ni * 16 + rA;
            const int bb = bm0 + m0 + mi * 16 + (lane >> 4) * 4;
            const f32x4 a = acc[mi][ni];
            for (int r = 0; r < 4; ++r)
                Y[(size_t)(bb + r) * D_SZ + dd] = a[r];
        }
}

extern "C" void kernel_launch(void* const* d_in, const int* in_sizes, int n_in,
                              void* d_out, int out_size, void* d_ws, size_t ws_size,
                              hipStream_t stream) {
    (void)in_sizes; (void)n_in; (void)out_size; (void)ws_size;
    const float* X = (const float*)d_in[0];
    const float* W = (const float*)d_in[1];
    float* Y = (float*)d_out;
    char* ws = (char*)d_ws;

    float* L = (float*)ws;                                      // 64 MB (logits + embedded a16)
    _Float16* wh = (_Float16*)(ws + (size_t)64 * 1024 * 1024);  // 1 MB
    _Float16* wt = wh + (size_t)N_SZ * D_SZ;                    // 1 MB
    float* ww = (float*)(wt + (size_t)N_SZ * D_SZ);             // 4 KB
    _Float16* xh = (_Float16*)((char*)ww + 4096);               // 16 MB

    prep_w<<<N_SZ, 256, 0, stream>>>(W, wh, wt, ww);
    prep_x<<<(B_SZ * D_SZ) / (256 * 8), 256, 0, stream>>>(X, xh);
    gemm1<<<dim3(N_SZ / 128, B_SZ / 128), 256, 0, stream>>>(xh, wh, ww, L);
    softsm<<<B_SZ, 256, 0, stream>>>(L);
    gemm2<<<dim3(D_SZ / 128, B_SZ / 128), 256, 0, stream>>>((const char*)L, wt, Y);
}

// Round 7
// 99.542 us; speedup vs baseline: 2.1863x; 1.0598x over previous
//
#include <hip/hip_runtime.h>
#include <hip/hip_bf16.h>
#include <stdint.h>

#define B_SZ 16384
#define D_SZ 512
#define N_SZ 1024

using f16x8 = __attribute__((ext_vector_type(8))) _Float16;
using f16x4 = __attribute__((ext_vector_type(4))) _Float16;
using f32x4 = __attribute__((ext_vector_type(4))) float;

typedef unsigned int u32_as1 __attribute__((address_space(1)));
typedef unsigned int u32_as3 __attribute__((address_space(3)));

__device__ __forceinline__ void gload16(const void* g, void* lds_base) {
    __builtin_amdgcn_global_load_lds((const u32_as1*)g, (u32_as3*)lds_base, 16, 0, 0);
}

// ---- merged prep: blocks [0,1024) do W; blocks [1024,5120) do X f32->fp16 ----
__global__ __launch_bounds__(256) void prep(
    const float* __restrict__ W, const float* __restrict__ X,
    _Float16* __restrict__ wh, _Float16* __restrict__ wt,
    float* __restrict__ ww, _Float16* __restrict__ xh) {
    __shared__ float part[4];
    const int bid = blockIdx.x;
    const int t = threadIdx.x;
    if (bid < N_SZ) {
        const int n = bid;
        const float2 v = *reinterpret_cast<const float2*>(&W[(size_t)n * D_SZ + t * 2]);
        _Float16 h0 = (_Float16)v.x, h1 = (_Float16)v.y;
        wh[(size_t)n * D_SZ + t * 2] = h0;
        wh[(size_t)n * D_SZ + t * 2 + 1] = h1;
        wt[(size_t)(t * 2) * N_SZ + n] = h0;
        wt[(size_t)(t * 2 + 1) * N_SZ + n] = h1;
        float s = v.x * v.x + v.y * v.y;
        for (int o = 32; o; o >>= 1) s += __shfl_xor(s, o);
        if ((t & 63) == 0) part[t >> 6] = s;
        __syncthreads();
        if (t == 0) ww[n] = part[0] + part[1] + part[2] + part[3];
    } else {
        const int b2 = bid - N_SZ;                       // 0..4095
        const int chunk = (b2 & 7) * 512 + (b2 >> 3);
        const size_t idx = ((size_t)chunk * 256 + t) * 8;
        const float4 a = *reinterpret_cast<const float4*>(&X[idx]);
        const float4 b = *reinterpret_cast<const float4*>(&X[idx + 4]);
        f16x8 h = {(_Float16)a.x, (_Float16)a.y, (_Float16)a.z, (_Float16)a.w,
                   (_Float16)b.x, (_Float16)b.y, (_Float16)b.z, (_Float16)b.w};
        *reinterpret_cast<f16x8*>(&xh[idx]) = h;
    }
}

// ---- GEMM1: L16[b,n] = fp16(4*(x_b . w_n) - 2*||w_n||^2); all-gload 2-phase ----
__global__ __launch_bounds__(256, 3) void gemm1(
    const _Float16* __restrict__ xh, const _Float16* __restrict__ wh,
    const float* __restrict__ ww, _Float16* __restrict__ L16) {
    __shared__ _Float16 smem[16384];  // K-loop: As(16KB)+Bs(16KB); epilogue: 128x128 f16
    const int tid = threadIdx.x;
    const int wid = tid >> 6, lane = tid & 63;
    const int raw = blockIdx.y * 8 + blockIdx.x;          // 0..1023
    const int wsw = (raw & 7) * 128 + (raw >> 3);         // bijective XCD chunking
    const int bn0 = (wsw & 7) * 128;
    const int bm0 = (wsw >> 3) * 128;
    const int m0 = (wid >> 1) * 64, n0 = (wid & 1) * 64;
    const int rA = lane & 15;
    const int cbr = (lane >> 4) * 16;
    const int rswz = ((rA >> 1) & 3) << 4;

    const int br0 = (wid * 2) * 16 + (lane >> 2);
    const int br1 = (wid * 2 + 1) * 16 + (lane >> 2);
    const int sg0 = ((lane & 3) ^ ((br0 >> 1) & 3)) * 8;
    const int sg1 = ((lane & 3) ^ ((br1 >> 1) & 3)) * 8;
    const int bdst0 = (wid * 2) * 1024;
    const int bdst1 = (wid * 2 + 1) * 1024;
    char* const As_b = (char*)smem;
    char* const Bs_b = (char*)smem + 16384;

    f32x4 acc[4][4];
    for (int mi = 0; mi < 4; ++mi)
        for (int ni = 0; ni < 4; ++ni) acc[mi][ni] = (f32x4){0.f, 0.f, 0.f, 0.f};

    gload16(&xh[(size_t)(bm0 + br0) * D_SZ + sg0], As_b + bdst0);
    gload16(&xh[(size_t)(bm0 + br1) * D_SZ + sg1], As_b + bdst1);
    gload16(&wh[(size_t)(bn0 + br0) * D_SZ + sg0], Bs_b + bdst0);
    gload16(&wh[(size_t)(bn0 + br1) * D_SZ + sg1], Bs_b + bdst1);
    __syncthreads();

    int cur = 0;
    for (int kt = 0; kt < 16; ++kt) {
        const int nxt = cur ^ 1;
        if (kt < 15) {
            const int gk = (kt + 1) * 32;
            gload16(&xh[(size_t)(bm0 + br0) * D_SZ + gk + sg0], As_b + nxt * 8192 + bdst0);
            gload16(&xh[(size_t)(bm0 + br1) * D_SZ + gk + sg1], As_b + nxt * 8192 + bdst1);
            gload16(&wh[(size_t)(bn0 + br0) * D_SZ + gk + sg0], Bs_b + nxt * 8192 + bdst0);
            gload16(&wh[(size_t)(bn0 + br1) * D_SZ + gk + sg1], Bs_b + nxt * 8192 + bdst1);
        }
        f16x8 af[4], bf[4];
        for (int mi = 0; mi < 4; ++mi)
            af[mi] = *reinterpret_cast<const f16x8*>(
                As_b + cur * 8192 + (m0 + mi * 16 + rA) * 64 + (cbr ^ rswz));
        for (int ni = 0; ni < 4; ++ni)
            bf[ni] = *reinterpret_cast<const f16x8*>(
                Bs_b + cur * 8192 + (n0 + ni * 16 + rA) * 64 + (cbr ^ rswz));
        for (int mi = 0; mi < 4; ++mi)
            for (int ni = 0; ni < 4; ++ni)
                acc[mi][ni] = __builtin_amdgcn_mfma_f32_16x16x32_f16(af[mi], bf[ni], acc[mi][ni], 0, 0, 0);
        __syncthreads();
        cur = nxt;
    }

    // epilogue: acc -> f16 via LDS transpose -> coalesced 16B row stores
    for (int mi = 0; mi < 4; ++mi)
        for (int ni = 0; ni < 4; ++ni) {
            const int ln = n0 + ni * 16 + rA;
            const float wwn = ww[bn0 + ln];
            const int lm = m0 + mi * 16 + (lane >> 4) * 4;
            const f32x4 a = acc[mi][ni];
            for (int r = 0; r < 4; ++r)
                smem[(lm + r) * 128 + ln] = (_Float16)(4.f * a[r] - 2.f * wwn);
        }
    __syncthreads();
    for (int c = 0; c < 8; ++c) {
        const int idx = c * 2048 + tid * 8;
        const int row = idx >> 7, col = idx & 127;
        const f16x8 v = *reinterpret_cast<const f16x8*>(&smem[idx]);
        *reinterpret_cast<f16x8*>(&L16[(size_t)(bm0 + row) * N_SZ + bn0 + col]) = v;
    }
}

// ---- wave-parallel dual-axis softmax on fp16 logits; writes a16 IN PLACE ----
// Each block owns exactly one row: reads its 2KB fully (one read per thread),
// then overwrites the same bytes with fp16 a. No cross-thread/cross-block
// hazard; deterministic across replays.
__global__ __launch_bounds__(256) void softsm(_Float16* __restrict__ L16) {
    __shared__ float4 spart[4][8];
    __shared__ float mpart[4];
    __shared__ float Tp[4];
    const int t = threadIdx.x;
    const int w = t >> 6, lane = t & 63;
    const int g8 = t & 7;
    const int bid = blockIdx.x;
    const size_t row = (size_t)((bid & 7) * 2048 + (bid >> 3));
    const f16x4 lv = *reinterpret_cast<const f16x4*>(&L16[row * N_SZ + (size_t)t * 4]);
    const float v0 = (float)lv[0], v1 = (float)lv[1], v2 = (float)lv[2], v3 = (float)lv[3];

    float m = fmaxf(fmaxf(v0, v1), fmaxf(v2, v3));
    for (int o = 32; o; o >>= 1) m = fmaxf(m, __shfl_xor(m, o));
    if (lane == 0) mpart[w] = m;
    __syncthreads();
    m = fmaxf(fmaxf(mpart[0], mpart[1]), fmaxf(mpart[2], mpart[3]));

    const float u0 = __expf(v0 - m), u1 = __expf(v1 - m);
    const float u2 = __expf(v2 - m), u3 = __expf(v3 - m);
    float rs = (u0 + u1) + (u2 + u3);
    rs += __shfl_xor(rs, 1); rs += __shfl_xor(rs, 2); rs += __shfl_xor(rs, 4);
    float s0 = u0, s1 = u1, s2 = u2, s3 = u3;
    for (int o = 8; o <= 32; o <<= 1) {
        s0 += __shfl_xor(s0, o); s1 += __shfl_xor(s1, o);
        s2 += __shfl_xor(s2, o); s3 += __shfl_xor(s3, o);
    }
    if (lane < 8) spart[w][lane] = make_float4(s0, s1, s2, s3);
    __syncthreads();
    {
        const float4 q0 = spart[0][g8], q1 = spart[1][g8], q2 = spart[2][g8], q3 = spart[3][g8];
        s0 = (q0.x + q1.x) + (q2.x + q3.x);
        s1 = (q0.y + q1.y) + (q2.y + q3.y);
        s2 = (q0.z + q1.z) + (q2.z + q3.z);
        s3 = (q0.w + q1.w) + (q2.w + q3.w);
    }
    const float irs = __builtin_amdgcn_rcpf(rs);
    const float t0 = u0 * u0 * irs * __builtin_amdgcn_rcpf(s0);
    const float t1 = u1 * u1 * irs * __builtin_amdgcn_rcpf(s1);
    const float t2 = u2 * u2 * irs * __builtin_amdgcn_rcpf(s2);
    const float t3 = u3 * u3 * irs * __builtin_amdgcn_rcpf(s3);
    float sT = (t0 + t1) + (t2 + t3);
    for (int o = 1; o <= 32; o <<= 1) sT += __shfl_xor(sT, o);
    if (lane == 0) Tp[w] = sT;
    __syncthreads();
    const float T = (Tp[0] + Tp[1]) + (Tp[2] + Tp[3]);
    const float inv = __builtin_amdgcn_rcpf(T + 1e-8f);
    f16x4 o16 = {(_Float16)(t0 * inv), (_Float16)(t1 * inv),
                 (_Float16)(t2 * inv), (_Float16)(t3 * inv)};
    *reinterpret_cast<f16x4*>(&L16[row * N_SZ + (size_t)t * 4]) = o16;
}

// ---- GEMM2: Y[b,d] = sum_n a[b,n] * W[n,d]; 2-phase, all gload_lds ----
__global__ __launch_bounds__(256, 3) void gemm2(
    const _Float16* __restrict__ a16, const _Float16* __restrict__ wt,
    float* __restrict__ Y) {
    __shared__ _Float16 As[2 * 128 * 32];
    __shared__ _Float16 Bs[2 * 128 * 32];
    const int tid = threadIdx.x;
    const int wid = tid >> 6, lane = tid & 63;
    const int raw = blockIdx.y * 4 + blockIdx.x;          // 0..511
    const int wsw = (raw & 7) * 64 + (raw >> 3);          // bijective XCD chunking
    const int bn0 = (wsw & 3) * 128;  // d
    const int bm0 = (wsw >> 2) * 128; // b
    const int m0 = (wid >> 1) * 64, n0 = (wid & 1) * 64;
    const int rA = lane & 15;
    const int cbr = (lane >> 4) * 16;
    const int rswz = ((rA >> 1) & 3) << 4;

    const int br0 = (wid * 2) * 16 + (lane >> 2);
    const int br1 = (wid * 2 + 1) * 16 + (lane >> 2);
    const int sg0 = ((lane & 3) ^ ((br0 >> 1) & 3)) * 8;
    const int sg1 = ((lane & 3) ^ ((br1 >> 1) & 3)) * 8;
    const int bdst0 = (wid * 2) * 1024;
    const int bdst1 = (wid * 2 + 1) * 1024;
    char* const As_b = (char*)As;
    char* const Bs_b = (char*)Bs;

    f32x4 acc[4][4];
    for (int mi = 0; mi < 4; ++mi)
        for (int ni = 0; ni < 4; ++ni) acc[mi][ni] = (f32x4){0.f, 0.f, 0.f, 0.f};

    gload16(&a16[(size_t)(bm0 + br0) * N_SZ + sg0], As_b + bdst0);
    gload16(&a16[(size_t)(bm0 + br1) * N_SZ + sg1], As_b + bdst1);
    gload16(&wt[(size_t)(bn0 + br0) * N_SZ + sg0], Bs_b + bdst0);
    gload16(&wt[(size_t)(bn0 + br1) * N_SZ + sg1], Bs_b + bdst1);
    __syncthreads();

    int cur = 0;
    for (int kt = 0; kt < 32; ++kt) {
        const int nxt = cur ^ 1;
        if (kt < 31) {
            const int gk = (kt + 1) * 32;
            gload16(&a16[(size_t)(bm0 + br0) * N_SZ + gk + sg0], As_b + nxt * 8192 + bdst0);
            gload16(&a16[(size_t)(bm0 + br1) * N_SZ + gk + sg1], As_b + nxt * 8192 + bdst1);
            gload16(&wt[(size_t)(bn0 + br0) * N_SZ + gk + sg0], Bs_b + nxt * 8192 + bdst0);
            gload16(&wt[(size_t)(bn0 + br1) * N_SZ + gk + sg1], Bs_b + nxt * 8192 + bdst1);
        }
        f16x8 af[4], bf[4];
        for (int mi = 0; mi < 4; ++mi)
            af[mi] = *reinterpret_cast<const f16x8*>(
                As_b + cur * 8192 + (m0 + mi * 16 + rA) * 64 + (cbr ^ rswz));
        for (int ni = 0; ni < 4; ++ni)
            bf[ni] = *reinterpret_cast<const f16x8*>(
                Bs_b + cur * 8192 + (n0 + ni * 16 + rA) * 64 + (cbr ^ rswz));
        for (int mi = 0; mi < 4; ++mi)
            for (int ni = 0; ni < 4; ++ni)
                acc[mi][ni] = __builtin_amdgcn_mfma_f32_16x16x32_f16(af[mi], bf[ni], acc[mi][ni], 0, 0, 0);
        __syncthreads();
        cur = nxt;
    }
    for (int mi = 0; mi < 4; ++mi)
        for (int ni = 0; ni < 4; ++ni) {
            const int dd = bn0 + n0 + ni * 16 + rA;
            const int bb = bm0 + m0 + mi * 16 + (lane >> 4) * 4;
            const f32x4 a = acc[mi][ni];
            for (int r = 0; r < 4; ++r)
                Y[(size_t)(bb + r) * D_SZ + dd] = a[r];
        }
}

extern "C" void kernel_launch(void* const* d_in, const int* in_sizes, int n_in,
                              void* d_out, int out_size, void* d_ws, size_t ws_size,
                              hipStream_t stream) {
    (void)in_sizes; (void)n_in; (void)out_size; (void)ws_size;
    const float* X = (const float*)d_in[0];
    const float* W = (const float*)d_in[1];
    float* Y = (float*)d_out;
    char* ws = (char*)d_ws;

    // Workspace layout (total 50 MiB + 4 KiB):
    //   L16 [0, 32 MiB)      : B*N fp16 logits; softsm overwrites IN PLACE with a16
    //   wh  [32, 33 MiB)     : W fp16 [N][D]
    //   wt  [33, 34 MiB)     : W^T fp16 [D][N]
    //   ww  [34 MiB, +4 KiB) : ||w_n||^2 f32
    //   xh  [34 MiB+4K, 50 MiB+4K) : X fp16 [B][D]
    _Float16* L16 = (_Float16*)ws;
    _Float16* wh  = (_Float16*)(ws + (size_t)32 * 1024 * 1024);
    _Float16* wt  = (_Float16*)(ws + (size_t)33 * 1024 * 1024);
    float*    ww  = (float*)   (ws + (size_t)34 * 1024 * 1024);
    _Float16* xh  = (_Float16*)(ws + (size_t)34 * 1024 * 1024 + 4096);

    prep<<<N_SZ + 4096, 256, 0, stream>>>(W, X, wh, wt, ww, xh);
    gemm1<<<dim3(N_SZ / 128, B_SZ / 128), 256, 0, stream>>>(xh, wh, ww, L16);
    softsm<<<B_SZ, 256, 0, stream>>>(L16);
    gemm2<<<dim3(D_SZ / 128, B_SZ / 128), 256, 0, stream>>>(L16, wt, Y);
}

// Round 8
// 99.456 us; speedup vs baseline: 2.1882x; 1.0009x over previous
//
#include <hip/hip_runtime.h>
#include <hip/hip_bf16.h>
#include <stdint.h>

#define B_SZ 16384
#define D_SZ 512
#define N_SZ 1024

using f16x8 = __attribute__((ext_vector_type(8))) _Float16;
using f16x4 = __attribute__((ext_vector_type(4))) _Float16;
using f32x4 = __attribute__((ext_vector_type(4))) float;

typedef unsigned int u32_as1 __attribute__((address_space(1)));
typedef unsigned int u32_as3 __attribute__((address_space(3)));

__device__ __forceinline__ void gload16(const void* g, void* lds_base) {
    __builtin_amdgcn_global_load_lds((const u32_as1*)g, (u32_as3*)lds_base, 16, 0, 0);
}

__device__ __forceinline__ unsigned short f16bits(_Float16 h) {
    return __builtin_bit_cast(unsigned short, h);
}

// ---- merged prep ----
// blocks [0,32): W -> wh (f16), wt (f16 transposed via LDS, coalesced 64B rows),
//                ww (row norms). 32 n-rows per block.
// blocks [32, 32+4096): X f32 -> fp16, XCD-aligned with gemm1's consumer map.
__global__ __launch_bounds__(256) void prep(
    const float* __restrict__ W, const float* __restrict__ X,
    _Float16* __restrict__ wh, _Float16* __restrict__ wt,
    float* __restrict__ ww, _Float16* __restrict__ xh) {
    const int bid = blockIdx.x;
    const int t = threadIdx.x;
    if (bid < 32) {
        __shared__ unsigned int cells[512 * 17];
        const int n0 = bid * 32;
        const int np = t >> 4;       // n-pair index 0..15
        const int dc = t & 15;       // d-chunk 0..15 (32 cols each)
        const int na = n0 + 2 * np, nb = na + 1;
        const int d0 = dc * 32;
        float va[32], vb[32];
#pragma unroll
        for (int i = 0; i < 8; ++i) {
            *reinterpret_cast<float4*>(&va[i * 4]) =
                *reinterpret_cast<const float4*>(&W[(size_t)na * D_SZ + d0 + i * 4]);
            *reinterpret_cast<float4*>(&vb[i * 4]) =
                *reinterpret_cast<const float4*>(&W[(size_t)nb * D_SZ + d0 + i * 4]);
        }
        float sa = 0.f, sb = 0.f;
#pragma unroll
        for (int i = 0; i < 32; ++i) { sa += va[i] * va[i]; sb += vb[i] * vb[i]; }
        sa += __shfl_xor(sa, 1); sa += __shfl_xor(sa, 2);
        sa += __shfl_xor(sa, 4); sa += __shfl_xor(sa, 8);
        sb += __shfl_xor(sb, 1); sb += __shfl_xor(sb, 2);
        sb += __shfl_xor(sb, 4); sb += __shfl_xor(sb, 8);
        if (dc == 0) { ww[na] = sa; ww[nb] = sb; }
        // f16 conversions
        _Float16 ha[32], hb[32];
#pragma unroll
        for (int i = 0; i < 32; ++i) { ha[i] = (_Float16)va[i]; hb[i] = (_Float16)vb[i]; }
        // wh: same-row u32 pairs, 64B contiguous per row-chunk
        unsigned int pa[16], pb[16];
#pragma unroll
        for (int j = 0; j < 16; ++j) {
            pa[j] = (unsigned)f16bits(ha[2 * j]) | ((unsigned)f16bits(ha[2 * j + 1]) << 16);
            pb[j] = (unsigned)f16bits(hb[2 * j]) | ((unsigned)f16bits(hb[2 * j + 1]) << 16);
        }
        unsigned int* whU = reinterpret_cast<unsigned int*>(wh);
#pragma unroll
        for (int j = 0; j < 4; ++j) {
            *reinterpret_cast<uint4*>(&whU[((size_t)na * D_SZ + d0) / 2 + j * 4]) =
                make_uint4(pa[j * 4], pa[j * 4 + 1], pa[j * 4 + 2], pa[j * 4 + 3]);
            *reinterpret_cast<uint4*>(&whU[((size_t)nb * D_SZ + d0) / 2 + j * 4]) =
                make_uint4(pb[j * 4], pb[j * 4 + 1], pb[j * 4 + 2], pb[j * 4 + 3]);
        }
        // LDS cells: cell[d][np] = (f16 W[na][d], f16 W[nb][d]); slot XOR-permuted
#pragma unroll
        for (int k = 0; k < 32; ++k) {
            const int d = d0 + k;
            const unsigned u = (unsigned)f16bits(ha[k]) | ((unsigned)f16bits(hb[k]) << 16);
            cells[d * 17 + (np ^ ((d >> 5) & 15))] = u;
        }
        __syncthreads();
        // wt: thread stores rows d = 2t, 2t+1; 64B contiguous each
        for (int rr = 0; rr < 2; ++rr) {
            const int d = 2 * t + rr;
            const int px = (d >> 5) & 15;
            unsigned int buf[16];
#pragma unroll
            for (int j = 0; j < 16; ++j) buf[j] = cells[d * 17 + (j ^ px)];
            unsigned int* wtU = reinterpret_cast<unsigned int*>(wt);
#pragma unroll
            for (int j = 0; j < 4; ++j)
                *reinterpret_cast<uint4*>(&wtU[((size_t)d * N_SZ + n0) / 2 + j * 4]) =
                    make_uint4(buf[j * 4], buf[j * 4 + 1], buf[j * 4 + 2], buf[j * 4 + 3]);
        }
    } else {
        const int b2 = bid - 32;                         // 0..4095
        const int chunk = (b2 & 7) * 512 + (b2 >> 3);    // XCD-aligned
        const size_t idx = ((size_t)chunk * 256 + t) * 8;
        const float4 a = *reinterpret_cast<const float4*>(&X[idx]);
        const float4 b = *reinterpret_cast<const float4*>(&X[idx + 4]);
        f16x8 h = {(_Float16)a.x, (_Float16)a.y, (_Float16)a.z, (_Float16)a.w,
                   (_Float16)b.x, (_Float16)b.y, (_Float16)b.z, (_Float16)b.w};
        *reinterpret_cast<f16x8*>(&xh[idx]) = h;
    }
}

// ---- GEMM1: L16[b,n] = fp16(4*(x_b . w_n) - 2*||w_n||^2); all-gload 2-phase ----
__global__ __launch_bounds__(256, 4) void gemm1(
    const _Float16* __restrict__ xh, const _Float16* __restrict__ wh,
    const float* __restrict__ ww, _Float16* __restrict__ L16) {
    __shared__ _Float16 smem[16384];  // K-loop: As(16KB)+Bs(16KB); epilogue: 128x128 f16
    const int tid = threadIdx.x;
    const int wid = tid >> 6, lane = tid & 63;
    const int raw = blockIdx.y * 8 + blockIdx.x;          // 0..1023
    const int wsw = (raw & 7) * 128 + (raw >> 3);         // bijective XCD chunking
    const int bn0 = (wsw & 7) * 128;
    const int bm0 = (wsw >> 3) * 128;
    const int m0 = (wid >> 1) * 64, n0 = (wid & 1) * 64;
    const int rA = lane & 15;
    const int cbr = (lane >> 4) * 16;
    const int rswz = ((rA >> 1) & 3) << 4;

    const int br0 = (wid * 2) * 16 + (lane >> 2);
    const int br1 = (wid * 2 + 1) * 16 + (lane >> 2);
    const int sg0 = ((lane & 3) ^ ((br0 >> 1) & 3)) * 8;
    const int sg1 = ((lane & 3) ^ ((br1 >> 1) & 3)) * 8;
    const int bdst0 = (wid * 2) * 1024;
    const int bdst1 = (wid * 2 + 1) * 1024;
    char* const As_b = (char*)smem;
    char* const Bs_b = (char*)smem + 16384;

    f32x4 acc[4][4];
    for (int mi = 0; mi < 4; ++mi)
        for (int ni = 0; ni < 4; ++ni) acc[mi][ni] = (f32x4){0.f, 0.f, 0.f, 0.f};

    gload16(&xh[(size_t)(bm0 + br0) * D_SZ + sg0], As_b + bdst0);
    gload16(&xh[(size_t)(bm0 + br1) * D_SZ + sg1], As_b + bdst1);
    gload16(&wh[(size_t)(bn0 + br0) * D_SZ + sg0], Bs_b + bdst0);
    gload16(&wh[(size_t)(bn0 + br1) * D_SZ + sg1], Bs_b + bdst1);
    __syncthreads();

    int cur = 0;
    for (int kt = 0; kt < 16; ++kt) {
        const int nxt = cur ^ 1;
        if (kt < 15) {
            const int gk = (kt + 1) * 32;
            gload16(&xh[(size_t)(bm0 + br0) * D_SZ + gk + sg0], As_b + nxt * 8192 + bdst0);
            gload16(&xh[(size_t)(bm0 + br1) * D_SZ + gk + sg1], As_b + nxt * 8192 + bdst1);
            gload16(&wh[(size_t)(bn0 + br0) * D_SZ + gk + sg0], Bs_b + nxt * 8192 + bdst0);
            gload16(&wh[(size_t)(bn0 + br1) * D_SZ + gk + sg1], Bs_b + nxt * 8192 + bdst1);
        }
        f16x8 af[4], bf[4];
        for (int mi = 0; mi < 4; ++mi)
            af[mi] = *reinterpret_cast<const f16x8*>(
                As_b + cur * 8192 + (m0 + mi * 16 + rA) * 64 + (cbr ^ rswz));
        for (int ni = 0; ni < 4; ++ni)
            bf[ni] = *reinterpret_cast<const f16x8*>(
                Bs_b + cur * 8192 + (n0 + ni * 16 + rA) * 64 + (cbr ^ rswz));
        for (int mi = 0; mi < 4; ++mi)
            for (int ni = 0; ni < 4; ++ni)
                acc[mi][ni] = __builtin_amdgcn_mfma_f32_16x16x32_f16(af[mi], bf[ni], acc[mi][ni], 0, 0, 0);
        __syncthreads();
        cur = nxt;
    }

    // epilogue: acc -> f16 via LDS transpose -> coalesced 16B row stores
    for (int mi = 0; mi < 4; ++mi)
        for (int ni = 0; ni < 4; ++ni) {
            const int ln = n0 + ni * 16 + rA;
            const float wwn = ww[bn0 + ln];
            const int lm = m0 + mi * 16 + (lane >> 4) * 4;
            const f32x4 a = acc[mi][ni];
            for (int r = 0; r < 4; ++r)
                smem[(lm + r) * 128 + ln] = (_Float16)(4.f * a[r] - 2.f * wwn);
        }
    __syncthreads();
    for (int c = 0; c < 8; ++c) {
        const int idx = c * 2048 + tid * 8;
        const int row = idx >> 7, col = idx & 127;
        const f16x8 v = *reinterpret_cast<const f16x8*>(&smem[idx]);
        *reinterpret_cast<f16x8*>(&L16[(size_t)(bm0 + row) * N_SZ + bn0 + col]) = v;
    }
}

// ---- wave-parallel dual-axis softmax; 2 rows per 512-thread block; in-place ----
__global__ __launch_bounds__(512) void softsm(_Float16* __restrict__ L16) {
    __shared__ float4 spart[2][4][8];
    __shared__ float mpart[2][4];
    __shared__ float Tp[2][4];
    const int h = threadIdx.x >> 8;
    const int t = threadIdx.x & 255;
    const int w = t >> 6, lane = t & 63;
    const int g8 = t & 7;
    const int bid = blockIdx.x;  // 0..8191
    const size_t row = (size_t)(bid & 7) * 2048 + (size_t)(bid >> 3) * 2 + h;
    const f16x4 lv = *reinterpret_cast<const f16x4*>(&L16[row * N_SZ + (size_t)t * 4]);
    const float v0 = (float)lv[0], v1 = (float)lv[1], v2 = (float)lv[2], v3 = (float)lv[3];

    float m = fmaxf(fmaxf(v0, v1), fmaxf(v2, v3));
    for (int o = 32; o; o >>= 1) m = fmaxf(m, __shfl_xor(m, o));
    if (lane == 0) mpart[h][w] = m;
    __syncthreads();
    m = fmaxf(fmaxf(mpart[h][0], mpart[h][1]), fmaxf(mpart[h][2], mpart[h][3]));

    const float u0 = __expf(v0 - m), u1 = __expf(v1 - m);
    const float u2 = __expf(v2 - m), u3 = __expf(v3 - m);
    float rs = (u0 + u1) + (u2 + u3);
    rs += __shfl_xor(rs, 1); rs += __shfl_xor(rs, 2); rs += __shfl_xor(rs, 4);
    float s0 = u0, s1 = u1, s2 = u2, s3 = u3;
    for (int o = 8; o <= 32; o <<= 1) {
        s0 += __shfl_xor(s0, o); s1 += __shfl_xor(s1, o);
        s2 += __shfl_xor(s2, o); s3 += __shfl_xor(s3, o);
    }
    if (lane < 8) spart[h][w][lane] = make_float4(s0, s1, s2, s3);
    __syncthreads();
    {
        const float4 q0 = spart[h][0][g8], q1 = spart[h][1][g8];
        const float4 q2 = spart[h][2][g8], q3 = spart[h][3][g8];
        s0 = (q0.x + q1.x) + (q2.x + q3.x);
        s1 = (q0.y + q1.y) + (q2.y + q3.y);
        s2 = (q0.z + q1.z) + (q2.z + q3.z);
        s3 = (q0.w + q1.w) + (q2.w + q3.w);
    }
    const float irs = __builtin_amdgcn_rcpf(rs);
    const float t0 = u0 * u0 * irs * __builtin_amdgcn_rcpf(s0);
    const float t1 = u1 * u1 * irs * __builtin_amdgcn_rcpf(s1);
    const float t2 = u2 * u2 * irs * __builtin_amdgcn_rcpf(s2);
    const float t3 = u3 * u3 * irs * __builtin_amdgcn_rcpf(s3);
    float sT = (t0 + t1) + (t2 + t3);
    for (int o = 1; o <= 32; o <<= 1) sT += __shfl_xor(sT, o);
    if (lane == 0) Tp[h][w] = sT;
    __syncthreads();
    const float T = (Tp[h][0] + Tp[h][1]) + (Tp[h][2] + Tp[h][3]);
    const float inv = __builtin_amdgcn_rcpf(T + 1e-8f);
    f16x4 o16 = {(_Float16)(t0 * inv), (_Float16)(t1 * inv),
                 (_Float16)(t2 * inv), (_Float16)(t3 * inv)};
    *reinterpret_cast<f16x4*>(&L16[row * N_SZ + (size_t)t * 4]) = o16;
}

// ---- GEMM2: Y[b,d] = sum_n a[b,n] * W[n,d]; 2-phase, all gload_lds ----
__global__ __launch_bounds__(256, 4) void gemm2(
    const _Float16* __restrict__ a16, const _Float16* __restrict__ wt,
    float* __restrict__ Y) {
    __shared__ _Float16 As[2 * 128 * 32];
    __shared__ _Float16 Bs[2 * 128 * 32];
    const int tid = threadIdx.x;
    const int wid = tid >> 6, lane = tid & 63;
    const int raw = blockIdx.y * 4 + blockIdx.x;          // 0..511
    const int wsw = (raw & 7) * 64 + (raw >> 3);          // bijective XCD chunking
    const int bn0 = (wsw & 3) * 128;  // d
    const int bm0 = (wsw >> 2) * 128; // b
    const int m0 = (wid >> 1) * 64, n0 = (wid & 1) * 64;
    const int rA = lane & 15;
    const int cbr = (lane >> 4) * 16;
    const int rswz = ((rA >> 1) & 3) << 4;

    const int br0 = (wid * 2) * 16 + (lane >> 2);
    const int br1 = (wid * 2 + 1) * 16 + (lane >> 2);
    const int sg0 = ((lane & 3) ^ ((br0 >> 1) & 3)) * 8;
    const int sg1 = ((lane & 3) ^ ((br1 >> 1) & 3)) * 8;
    const int bdst0 = (wid * 2) * 1024;
    const int bdst1 = (wid * 2 + 1) * 1024;
    char* const As_b = (char*)As;
    char* const Bs_b = (char*)Bs;

    f32x4 acc[4][4];
    for (int mi = 0; mi < 4; ++mi)
        for (int ni = 0; ni < 4; ++ni) acc[mi][ni] = (f32x4){0.f, 0.f, 0.f, 0.f};

    gload16(&a16[(size_t)(bm0 + br0) * N_SZ + sg0], As_b + bdst0);
    gload16(&a16[(size_t)(bm0 + br1) * N_SZ + sg1], As_b + bdst1);
    gload16(&wt[(size_t)(bn0 + br0) * N_SZ + sg0], Bs_b + bdst0);
    gload16(&wt[(size_t)(bn0 + br1) * N_SZ + sg1], Bs_b + bdst1);
    __syncthreads();

    int cur = 0;
    for (int kt = 0; kt < 32; ++kt) {
        const int nxt = cur ^ 1;
        if (kt < 31) {
            const int gk = (kt + 1) * 32;
            gload16(&a16[(size_t)(bm0 + br0) * N_SZ + gk + sg0], As_b + nxt * 8192 + bdst0);
            gload16(&a16[(size_t)(bm0 + br1) * N_SZ + gk + sg1], As_b + nxt * 8192 + bdst1);
            gload16(&wt[(size_t)(bn0 + br0) * N_SZ + gk + sg0], Bs_b + nxt * 8192 + bdst0);
            gload16(&wt[(size_t)(bn0 + br1) * N_SZ + gk + sg1], Bs_b + nxt * 8192 + bdst1);
        }
        f16x8 af[4], bf[4];
        for (int mi = 0; mi < 4; ++mi)
            af[mi] = *reinterpret_cast<const f16x8*>(
                As_b + cur * 8192 + (m0 + mi * 16 + rA) * 64 + (cbr ^ rswz));
        for (int ni = 0; ni < 4; ++ni)
            bf[ni] = *reinterpret_cast<const f16x8*>(
                Bs_b + cur * 8192 + (n0 + ni * 16 + rA) * 64 + (cbr ^ rswz));
        for (int mi = 0; mi < 4; ++mi)
            for (int ni = 0; ni < 4; ++ni)
                acc[mi][ni] = __builtin_amdgcn_mfma_f32_16x16x32_f16(af[mi], bf[ni], acc[mi][ni], 0, 0, 0);
        __syncthreads();
        cur = nxt;
    }
    for (int mi = 0; mi < 4; ++mi)
        for (int ni = 0; ni < 4; ++ni) {
            const int dd = bn0 + n0 + ni * 16 + rA;
            const int bb = bm0 + m0 + mi * 16 + (lane >> 4) * 4;
            const f32x4 a = acc[mi][ni];
            for (int r = 0; r < 4; ++r)
                Y[(size_t)(bb + r) * D_SZ + dd] = a[r];
        }
}

extern "C" void kernel_launch(void* const* d_in, const int* in_sizes, int n_in,
                              void* d_out, int out_size, void* d_ws, size_t ws_size,
                              hipStream_t stream) {
    (void)in_sizes; (void)n_in; (void)out_size; (void)ws_size;
    const float* X = (const float*)d_in[0];
    const float* W = (const float*)d_in[1];
    float* Y = (float*)d_out;
    char* ws = (char*)d_ws;

    // Workspace layout (total ~50 MiB):
    //   L16 [0, 32 MiB)      : B*N fp16 logits; softsm overwrites IN PLACE with a16
    //   wh  [32, 33 MiB)     : W fp16 [N][D]
    //   wt  [33, 34 MiB)     : W^T fp16 [D][N]
    //   ww  [34 MiB, +4 KiB) : ||w_n||^2 f32
    //   xh  [34 MiB+4K, ...) : X fp16 [B][D]
    _Float16* L16 = (_Float16*)ws;
    _Float16* wh  = (_Float16*)(ws + (size_t)32 * 1024 * 1024);
    _Float16* wt  = (_Float16*)(ws + (size_t)33 * 1024 * 1024);
    float*    ww  = (float*)   (ws + (size_t)34 * 1024 * 1024);
    _Float16* xh  = (_Float16*)(ws + (size_t)34 * 1024 * 1024 + 4096);

    prep<<<32 + 4096, 256, 0, stream>>>(W, X, wh, wt, ww, xh);
    gemm1<<<dim3(N_SZ / 128, B_SZ / 128), 256, 0, stream>>>(xh, wh, ww, L16);
    softsm<<<B_SZ / 2, 512, 0, stream>>>(L16);
    gemm2<<<dim3(D_SZ / 128, B_SZ / 128), 256, 0, stream>>>(L16, wt, Y);
}